// Round 1
// baseline (23137.639 us; speedup 1.0000x reference)
//
#include <hip/hip_runtime.h>
#include <math.h>

// Problem constants (reference: B,T,D=16,512,256; HS=512, D_A=64, R=8)
#define BB 16
#define TT 512
#define DD 256
#define HS 512
#define DA 64
#define RR 8
#define G4H 2048   // 4*HS

// -------- workspace layout (float offsets) --------
// s     :        0  (B*T*R      =    65536)
// e     :    65536  (B*T*R      =    65536)
// inv   :   131072  (B*T*R      =    65536)
// M     :   196608  (B*T*D      =  2097152)
// gates :  2293760  (B*T*4H     = 16777216)
// hbuf  : 19070976  (2*B*HS     =    16384)
// cnt   : 19087360  (T uints    =      512)
// total ~ 76.4 MB

// ============================================================
// K1: s[b,t,r] = tanh(x[b,t,:] @ w1 + b1) @ w2 + b2
// one wave per (b,t); lane = hidden unit (DA==64)
// ============================================================
__global__ __launch_bounds__(256) void k1_score(
    const float* __restrict__ x, const float* __restrict__ w1,
    const float* __restrict__ b1, const float* __restrict__ w2,
    const float* __restrict__ b2, float* __restrict__ s_out) {
  const int wave = threadIdx.x >> 6;
  const int lane = threadIdx.x & 63;
  for (int i = 0; i < 4; ++i) {
    const int bt = blockIdx.x * 16 + wave * 4 + i;  // grid=512 -> 8192 bt
    const float* xr = x + bt * DD;
    float acc = b1[lane];
    #pragma unroll 4
    for (int d = 0; d < DD; ++d)
      acc = fmaf(xr[d], w1[d * DA + lane], acc);   // w1 coalesced over lanes
    const float a = tanhf(acc);
    #pragma unroll
    for (int r = 0; r < RR; ++r) {
      float v = a * w2[lane * RR + r];
      for (int off = 32; off > 0; off >>= 1) v += __shfl_xor(v, off);
      if (lane == 0) s_out[bt * RR + r] = v + b2[r];
    }
  }
}

// ============================================================
// K2: per (b,r): m=max_t s; e=exp(s-m); den=inclusive prefix sum;
// store e and 1/den.  grid = B*R = 128 blocks, 512 threads
// ============================================================
__global__ __launch_bounds__(512) void k2_prefix(
    const float* __restrict__ s_in, float* __restrict__ e_out,
    float* __restrict__ inv_out) {
  const int b = blockIdx.x >> 3, r = blockIdx.x & 7;
  const int t = threadIdx.x;
  __shared__ float red[TT];
  __shared__ float buf[2][TT];
  const float v = s_in[(b * TT + t) * RR + r];
  red[t] = v;
  __syncthreads();
  for (int off = 256; off >= 1; off >>= 1) {
    if (t < off) red[t] = fmaxf(red[t], red[t + off]);
    __syncthreads();
  }
  const float m = red[0];
  const float e = expf(v - m);
  int p = 0;
  buf[0][t] = e;
  __syncthreads();
  for (int off = 1; off < TT; off <<= 1) {
    const float add = (t >= off) ? buf[p][t - off] : 0.f;
    buf[1 - p][t] = buf[p][t] + add;
    __syncthreads();
    p ^= 1;
  }
  const float den = buf[p][t];
  e_out[(b * TT + t) * RR + r] = e;
  inv_out[(b * TT + t) * RR + r] = 1.0f / den;
}

// ============================================================
// K3: M[b,t,d] = (1/R) * sum_r inv[t,r] * prefix_j<=t( e[j,r]*x[b,j,d] )
// scan over t.  grid = B = 16 blocks, 256 threads (thread = d)
// ============================================================
__global__ __launch_bounds__(256) void k3_mix(
    const float* __restrict__ x, const float* __restrict__ e_in,
    const float* __restrict__ inv_in, float* __restrict__ Mout) {
  const int b = blockIdx.x;
  const int d = threadIdx.x;
  __shared__ __align__(16) float el[TT * RR];
  __shared__ __align__(16) float il[TT * RR];
  for (int i = threadIdx.x; i < TT * RR; i += 256) {
    el[i] = e_in[b * TT * RR + i];
    il[i] = inv_in[b * TT * RR + i];
  }
  __syncthreads();
  float4 c0 = {0.f, 0.f, 0.f, 0.f}, c1 = {0.f, 0.f, 0.f, 0.f};
  for (int t = 0; t < TT; ++t) {
    const float xv = x[(b * TT + t) * DD + d];
    const float4 e0 = *(const float4*)&el[t * RR];
    const float4 e1 = *(const float4*)&el[t * RR + 4];
    const float4 i0 = *(const float4*)&il[t * RR];
    const float4 i1 = *(const float4*)&il[t * RR + 4];
    c0.x = fmaf(e0.x, xv, c0.x); c0.y = fmaf(e0.y, xv, c0.y);
    c0.z = fmaf(e0.z, xv, c0.z); c0.w = fmaf(e0.w, xv, c0.w);
    c1.x = fmaf(e1.x, xv, c1.x); c1.y = fmaf(e1.y, xv, c1.y);
    c1.z = fmaf(e1.z, xv, c1.z); c1.w = fmaf(e1.w, xv, c1.w);
    float msum = c0.x * i0.x + c0.y * i0.y + c0.z * i0.z + c0.w * i0.w;
    msum += c1.x * i1.x + c1.y * i1.y + c1.z * i1.z + c1.w * i1.w;
    Mout[(b * TT + t) * DD + d] = msum * 0.125f;
  }
}

// ============================================================
// K4: gates = M(8192x256) @ W_ih(256x2048) + bias   (fp32 SGEMM)
// 128x128 tile, BK=16, (4+4)x(4+4) micro-tile. grid = 64*16 = 1024
// ============================================================
__global__ __launch_bounds__(256) void k4_gemm(
    const float* __restrict__ A, const float* __restrict__ Bw,
    const float* __restrict__ bias, float* __restrict__ C) {
  const int bn = blockIdx.x & 15;
  const int bm = blockIdx.x >> 4;
  const int tid = threadIdx.x;
  const int tx = tid & 15, ty = tid >> 4;
  __shared__ __align__(16) float As[16][132];
  __shared__ __align__(16) float Bs[16][132];
  const int row0 = bm * 128, col0 = bn * 128;

  float acc[2][4][2][4];
  #pragma unroll
  for (int a = 0; a < 2; ++a)
    #pragma unroll
    for (int i = 0; i < 4; ++i)
      #pragma unroll
      for (int q = 0; q < 2; ++q)
        #pragma unroll
        for (int j = 0; j < 4; ++j) acc[a][i][q][j] = 0.f;

  const int arow = tid >> 1, akc = (tid & 1) * 8;
  const int bkr = tid >> 4, bcc = (tid & 15) * 8;

  for (int k0 = 0; k0 < 256; k0 += 16) {
    const float4 a0 = *(const float4*)&A[(row0 + arow) * 256 + k0 + akc];
    const float4 a1 = *(const float4*)&A[(row0 + arow) * 256 + k0 + akc + 4];
    const float4 b0 = *(const float4*)&Bw[(k0 + bkr) * 2048 + col0 + bcc];
    const float4 b1 = *(const float4*)&Bw[(k0 + bkr) * 2048 + col0 + bcc + 4];
    __syncthreads();
    As[akc + 0][arow] = a0.x; As[akc + 1][arow] = a0.y;
    As[akc + 2][arow] = a0.z; As[akc + 3][arow] = a0.w;
    As[akc + 4][arow] = a1.x; As[akc + 5][arow] = a1.y;
    As[akc + 6][arow] = a1.z; As[akc + 7][arow] = a1.w;
    *(float4*)&Bs[bkr][bcc] = b0;
    *(float4*)&Bs[bkr][bcc + 4] = b1;
    __syncthreads();
    #pragma unroll
    for (int kk = 0; kk < 16; ++kk) {
      float av[8], bv[8];
      *(float4*)&av[0] = *(const float4*)&As[kk][ty * 4];
      *(float4*)&av[4] = *(const float4*)&As[kk][64 + ty * 4];
      *(float4*)&bv[0] = *(const float4*)&Bs[kk][tx * 4];
      *(float4*)&bv[4] = *(const float4*)&Bs[kk][64 + tx * 4];
      #pragma unroll
      for (int a = 0; a < 2; ++a)
        #pragma unroll
        for (int i = 0; i < 4; ++i)
          #pragma unroll
          for (int q = 0; q < 2; ++q)
            #pragma unroll
            for (int j = 0; j < 4; ++j)
              acc[a][i][q][j] = fmaf(av[a * 4 + i], bv[q * 4 + j], acc[a][i][q][j]);
    }
  }
  const float4 bias0 = *(const float4*)&bias[col0 + tx * 4];
  const float4 bias1 = *(const float4*)&bias[col0 + 64 + tx * 4];
  #pragma unroll
  for (int a = 0; a < 2; ++a)
    #pragma unroll
    for (int i = 0; i < 4; ++i) {
      const int row = row0 + a * 64 + ty * 4 + i;
      float4 v0, v1;
      v0.x = acc[a][i][0][0] + bias0.x; v0.y = acc[a][i][0][1] + bias0.y;
      v0.z = acc[a][i][0][2] + bias0.z; v0.w = acc[a][i][0][3] + bias0.w;
      v1.x = acc[a][i][1][0] + bias1.x; v1.y = acc[a][i][1][1] + bias1.y;
      v1.z = acc[a][i][1][2] + bias1.z; v1.w = acc[a][i][1][3] + bias1.w;
      *(float4*)&C[row * 2048 + col0 + tx * 4] = v0;
      *(float4*)&C[row * 2048 + col0 + 64 + tx * 4] = v1;
    }
}

// ============================================================
// K5: sequential LSTM. 256 co-resident blocks (<= 256 CUs, spin-safe),
// block g owns hidden units {2g, 2g+1} (8 gate cols) for ALL 16 batches.
// W_hh slice LDS-resident (16 KB); h exchanged per step via double-buffered
// global hbuf with AGENT-scope atomics + per-step arrival counter.
// ============================================================
__global__ __launch_bounds__(128) void k5_lstm(
    const float* __restrict__ gates, const float* __restrict__ whh,
    float* __restrict__ out, float* hbuf, unsigned int* cnt) {
  const int g = blockIdx.x;            // 0..255
  const int tid = threadIdx.x;         // 128 threads
  const int b = tid >> 3, u = tid & 7; // u = gate*2 + j
  const int j0 = g * 2;
  __shared__ __align__(16) float Wl[8][516];   // [u][k], pad 4 -> conflict-free
  __shared__ __align__(16) float hl[16][516];  // [b][k], 2-way (free)
  __shared__ float glds[16][8];
  __shared__ float cl[16][2];

  // stage W_hh slice (once; reused 512 steps)
  for (int i = tid; i < 8 * 512; i += 128) {
    const int uu = i & 7, k = i >> 3;
    const int col = (uu >> 1) * HS + j0 + (uu & 1);
    Wl[uu][k] = whh[k * G4H + col];
  }
  if (tid < 32) cl[tid >> 1][tid & 1] = 0.f;
  __syncthreads();

  const int mycol = (u >> 1) * HS + j0 + (u & 1);
  const float* hp = &hl[b][0];
  const float* wp = &Wl[u][0];

  for (int t = 0; t < TT; ++t) {
    const float gxv = gates[(b * TT + t) * G4H + mycol];  // issue early
    float acc = gxv;
    if (t > 0) {
      if (tid == 0) {
        while (__hip_atomic_load(&cnt[t - 1], __ATOMIC_ACQUIRE,
                                 __HIP_MEMORY_SCOPE_AGENT) < 256u)
          __builtin_amdgcn_s_sleep(2);
      }
      __syncthreads();
      // coherent reload of full h into LDS
      const float* hsrc = hbuf + ((t - 1) & 1) * (BB * HS);
      for (int i = tid; i < BB * HS; i += 128) {
        const unsigned int bits = __hip_atomic_load(
            (const unsigned int*)&hsrc[i], __ATOMIC_RELAXED,
            __HIP_MEMORY_SCOPE_AGENT);
        hl[i >> 9][i & 511] = __uint_as_float(bits);
      }
      __syncthreads();
      float4 a4 = {0.f, 0.f, 0.f, 0.f};
      #pragma unroll 4
      for (int k = 0; k < HS; k += 4) {
        const float4 hv = *(const float4*)(hp + k);
        const float4 wv = *(const float4*)(wp + k);
        a4.x = fmaf(hv.x, wv.x, a4.x);
        a4.y = fmaf(hv.y, wv.y, a4.y);
        a4.z = fmaf(hv.z, wv.z, a4.z);
        a4.w = fmaf(hv.w, wv.w, a4.w);
      }
      acc += (a4.x + a4.y) + (a4.z + a4.w);
    }
    glds[b][u] = acc;
    __syncthreads();
    if (tid < 32) {
      const int bb = tid >> 1, jj = tid & 1;
      const float iv = glds[bb][0 + jj];
      const float fv = glds[bb][2 + jj];
      const float gv = glds[bb][4 + jj];
      const float ov = glds[bb][6 + jj];
      const float ig = 1.f / (1.f + expf(-iv));
      const float fg = 1.f / (1.f + expf(-fv));
      const float gg = tanhf(gv);
      const float og = 1.f / (1.f + expf(-ov));
      const float c = fg * cl[bb][jj] + ig * gg;
      cl[bb][jj] = c;
      const float h = og * tanhf(c);
      const int unit = j0 + jj;
      out[(bb * TT + t) * HS + unit] = h;  // hidden_seq
      float* hdst = hbuf + (t & 1) * (BB * HS);
      __hip_atomic_store((unsigned int*)&hdst[bb * HS + unit],
                         __float_as_uint(h), __ATOMIC_RELAXED,
                         __HIP_MEMORY_SCOPE_AGENT);
      if (t == TT - 1) {
        out[BB * TT * HS + bb * HS + unit] = h;            // h_t
        out[BB * TT * HS + BB * HS + bb * HS + unit] = c;  // c_t
      }
    }
    __threadfence();  // push hbuf stores to device scope
    __syncthreads();
    if (tid == 0)
      __hip_atomic_fetch_add(&cnt[t], 1u, __ATOMIC_RELEASE,
                             __HIP_MEMORY_SCOPE_AGENT);
  }
}

// ============================================================
extern "C" void kernel_launch(void* const* d_in, const int* in_sizes, int n_in,
                              void* d_out, int out_size, void* d_ws,
                              size_t ws_size, hipStream_t stream) {
  const float* x    = (const float*)d_in[0];
  const float* w1   = (const float*)d_in[1];
  const float* b1   = (const float*)d_in[2];
  const float* w2   = (const float*)d_in[3];
  const float* b2   = (const float*)d_in[4];
  const float* wih  = (const float*)d_in[5];
  const float* whh  = (const float*)d_in[6];
  const float* bias = (const float*)d_in[7];
  float* out = (float*)d_out;

  float* ws = (float*)d_ws;
  float* s_buf  = ws;
  float* e_buf  = ws + 65536;
  float* i_buf  = ws + 131072;
  float* M_buf  = ws + 196608;
  float* g_buf  = ws + 2293760;
  float* h_buf  = ws + 19070976;
  unsigned int* cnt = (unsigned int*)(ws + 19087360);

  // per-step arrival counters must be zero every call (ws re-poisoned 0xAA)
  hipMemsetAsync(cnt, 0, TT * sizeof(unsigned int), stream);

  k1_score<<<512, 256, 0, stream>>>(x, w1, b1, w2, b2, s_buf);
  k2_prefix<<<BB * RR, 512, 0, stream>>>(s_buf, e_buf, i_buf);
  k3_mix<<<BB, 256, 0, stream>>>(x, e_buf, i_buf, M_buf);
  k4_gemm<<<64 * 16, 256, 0, stream>>>(M_buf, wih, bias, g_buf);
  k5_lstm<<<256, 128, 0, stream>>>(g_buf, whh, out, h_buf, cnt);
}

// Round 2
// 14459.499 us; speedup vs baseline: 1.6002x; 1.6002x over previous
//
#include <hip/hip_runtime.h>
#include <math.h>

// Problem constants (reference: B,T,D=16,512,256; HS=512, D_A=64, R=8)
#define BB 16
#define TT 512
#define DD 256
#define HS 512
#define DA 64
#define RR 8
#define G4H 2048   // 4*HS

// -------- workspace layout (float offsets) --------
// s     :        0  (B*T*R      =    65536)
// e     :    65536  (B*T*R      =    65536)
// inv   :   131072  (B*T*R      =    65536)
// M     :   196608  (B*T*D      =  2097152)
// gates :  2293760  (B*T*4H     = 16777216)
// hbuf  : 19070976  (2*B*HS     =    16384)
// flags : 19087360  (256 uints)

// ============================================================
// K1: s[b,t,r] = tanh(x[b,t,:] @ w1 + b1) @ w2 + b2
// ============================================================
__global__ __launch_bounds__(256) void k1_score(
    const float* __restrict__ x, const float* __restrict__ w1,
    const float* __restrict__ b1, const float* __restrict__ w2,
    const float* __restrict__ b2, float* __restrict__ s_out) {
  const int wave = threadIdx.x >> 6;
  const int lane = threadIdx.x & 63;
  for (int i = 0; i < 4; ++i) {
    const int bt = blockIdx.x * 16 + wave * 4 + i;  // grid=512 -> 8192 bt
    const float* xr = x + bt * DD;
    float acc = b1[lane];
    #pragma unroll 4
    for (int d = 0; d < DD; ++d)
      acc = fmaf(xr[d], w1[d * DA + lane], acc);   // w1 coalesced over lanes
    const float a = tanhf(acc);
    #pragma unroll
    for (int r = 0; r < RR; ++r) {
      float v = a * w2[lane * RR + r];
      for (int off = 32; off > 0; off >>= 1) v += __shfl_xor(v, off);
      if (lane == 0) s_out[bt * RR + r] = v + b2[r];
    }
  }
}

// ============================================================
// K2: per (b,r): m=max_t s; e=exp(s-m); den=inclusive prefix sum
// ============================================================
__global__ __launch_bounds__(512) void k2_prefix(
    const float* __restrict__ s_in, float* __restrict__ e_out,
    float* __restrict__ inv_out) {
  const int b = blockIdx.x >> 3, r = blockIdx.x & 7;
  const int t = threadIdx.x;
  __shared__ float red[TT];
  __shared__ float buf[2][TT];
  const float v = s_in[(b * TT + t) * RR + r];
  red[t] = v;
  __syncthreads();
  for (int off = 256; off >= 1; off >>= 1) {
    if (t < off) red[t] = fmaxf(red[t], red[t + off]);
    __syncthreads();
  }
  const float m = red[0];
  const float e = expf(v - m);
  int p = 0;
  buf[0][t] = e;
  __syncthreads();
  for (int off = 1; off < TT; off <<= 1) {
    const float add = (t >= off) ? buf[p][t - off] : 0.f;
    buf[1 - p][t] = buf[p][t] + add;
    __syncthreads();
    p ^= 1;
  }
  const float den = buf[p][t];
  e_out[(b * TT + t) * RR + r] = e;
  inv_out[(b * TT + t) * RR + r] = 1.0f / den;
}

// ============================================================
// K3: M[b,t,d] = (1/R) * sum_r inv[t,r] * prefix_j<=t( e[j,r]*x[b,j,d] )
// ============================================================
__global__ __launch_bounds__(256) void k3_mix(
    const float* __restrict__ x, const float* __restrict__ e_in,
    const float* __restrict__ inv_in, float* __restrict__ Mout) {
  const int b = blockIdx.x;
  const int d = threadIdx.x;
  __shared__ __align__(16) float el[TT * RR];
  __shared__ __align__(16) float il[TT * RR];
  for (int i = threadIdx.x; i < TT * RR; i += 256) {
    el[i] = e_in[b * TT * RR + i];
    il[i] = inv_in[b * TT * RR + i];
  }
  __syncthreads();
  float4 c0 = {0.f, 0.f, 0.f, 0.f}, c1 = {0.f, 0.f, 0.f, 0.f};
  for (int t = 0; t < TT; ++t) {
    const float xv = x[(b * TT + t) * DD + d];
    const float4 e0 = *(const float4*)&el[t * RR];
    const float4 e1 = *(const float4*)&el[t * RR + 4];
    const float4 i0 = *(const float4*)&il[t * RR];
    const float4 i1 = *(const float4*)&il[t * RR + 4];
    c0.x = fmaf(e0.x, xv, c0.x); c0.y = fmaf(e0.y, xv, c0.y);
    c0.z = fmaf(e0.z, xv, c0.z); c0.w = fmaf(e0.w, xv, c0.w);
    c1.x = fmaf(e1.x, xv, c1.x); c1.y = fmaf(e1.y, xv, c1.y);
    c1.z = fmaf(e1.z, xv, c1.z); c1.w = fmaf(e1.w, xv, c1.w);
    float msum = c0.x * i0.x + c0.y * i0.y + c0.z * i0.z + c0.w * i0.w;
    msum += c1.x * i1.x + c1.y * i1.y + c1.z * i1.z + c1.w * i1.w;
    Mout[(b * TT + t) * DD + d] = msum * 0.125f;
  }
}

// ============================================================
// K4: gates = M(8192x256) @ W_ih(256x2048) + bias   (fp32 SGEMM)
// ============================================================
__global__ __launch_bounds__(256) void k4_gemm(
    const float* __restrict__ A, const float* __restrict__ Bw,
    const float* __restrict__ bias, float* __restrict__ C) {
  const int bn = blockIdx.x & 15;
  const int bm = blockIdx.x >> 4;
  const int tid = threadIdx.x;
  const int tx = tid & 15, ty = tid >> 4;
  __shared__ __align__(16) float As[16][132];
  __shared__ __align__(16) float Bs[16][132];
  const int row0 = bm * 128, col0 = bn * 128;

  float acc[2][4][2][4];
  #pragma unroll
  for (int a = 0; a < 2; ++a)
    #pragma unroll
    for (int i = 0; i < 4; ++i)
      #pragma unroll
      for (int q = 0; q < 2; ++q)
        #pragma unroll
        for (int j = 0; j < 4; ++j) acc[a][i][q][j] = 0.f;

  const int arow = tid >> 1, akc = (tid & 1) * 8;
  const int bkr = tid >> 4, bcc = (tid & 15) * 8;

  for (int k0 = 0; k0 < 256; k0 += 16) {
    const float4 a0 = *(const float4*)&A[(row0 + arow) * 256 + k0 + akc];
    const float4 a1 = *(const float4*)&A[(row0 + arow) * 256 + k0 + akc + 4];
    const float4 b0 = *(const float4*)&Bw[(k0 + bkr) * 2048 + col0 + bcc];
    const float4 b1 = *(const float4*)&Bw[(k0 + bkr) * 2048 + col0 + bcc + 4];
    __syncthreads();
    As[akc + 0][arow] = a0.x; As[akc + 1][arow] = a0.y;
    As[akc + 2][arow] = a0.z; As[akc + 3][arow] = a0.w;
    As[akc + 4][arow] = a1.x; As[akc + 5][arow] = a1.y;
    As[akc + 6][arow] = a1.z; As[akc + 7][arow] = a1.w;
    *(float4*)&Bs[bkr][bcc] = b0;
    *(float4*)&Bs[bkr][bcc + 4] = b1;
    __syncthreads();
    #pragma unroll
    for (int kk = 0; kk < 16; ++kk) {
      float av[8], bv[8];
      *(float4*)&av[0] = *(const float4*)&As[kk][ty * 4];
      *(float4*)&av[4] = *(const float4*)&As[kk][64 + ty * 4];
      *(float4*)&bv[0] = *(const float4*)&Bs[kk][tx * 4];
      *(float4*)&bv[4] = *(const float4*)&Bs[kk][64 + tx * 4];
      #pragma unroll
      for (int a = 0; a < 2; ++a)
        #pragma unroll
        for (int i = 0; i < 4; ++i)
          #pragma unroll
          for (int q = 0; q < 2; ++q)
            #pragma unroll
            for (int j = 0; j < 4; ++j)
              acc[a][i][q][j] = fmaf(av[a * 4 + i], bv[q * 4 + j], acc[a][i][q][j]);
    }
  }
  const float4 bias0 = *(const float4*)&bias[col0 + tx * 4];
  const float4 bias1 = *(const float4*)&bias[col0 + 64 + tx * 4];
  #pragma unroll
  for (int a = 0; a < 2; ++a)
    #pragma unroll
    for (int i = 0; i < 4; ++i) {
      const int row = row0 + a * 64 + ty * 4 + i;
      float4 v0, v1;
      v0.x = acc[a][i][0][0] + bias0.x; v0.y = acc[a][i][0][1] + bias0.y;
      v0.z = acc[a][i][0][2] + bias0.z; v0.w = acc[a][i][0][3] + bias0.w;
      v1.x = acc[a][i][1][0] + bias1.x; v1.y = acc[a][i][1][1] + bias1.y;
      v1.z = acc[a][i][1][2] + bias1.z; v1.w = acc[a][i][1][3] + bias1.w;
      *(float4*)&C[row * 2048 + col0 + tx * 4] = v0;
      *(float4*)&C[row * 2048 + col0 + 64 + tx * 4] = v1;
    }
}

// ============================================================
// K5 v2: sequential LSTM, 256 co-resident blocks.
// Sync redesign vs v1 (which spent 37+ us/step serializing 256
// atomic fetch_adds on one LLC line):
//   - producer: h stored with agent-scope RELAXED atomic stores
//     (write-through to LLC), then ONE release store flags[g]=t+1.
//     flags are monotone -> no reset, no RMW, 256 distinct addrs.
//   - consumer: each thread acquire-polls 2 flags (distinct addrs,
//     parallel LLC reads), __syncthreads chains the happens-before
//     to the whole block, then bulk PLAIN float4 reload of h
//     (acquire invalidated L1/L2, so loads fetch fresh from LLC).
// ============================================================
__global__ __launch_bounds__(128) void k5_lstm(
    const float* __restrict__ gates, const float* __restrict__ whh,
    float* __restrict__ out, float* hbuf, unsigned int* flags) {
  const int g = blockIdx.x;            // 0..255
  const int tid = threadIdx.x;         // 128 threads
  const int b = tid >> 3, u = tid & 7; // u = gate*2 + j
  const int j0 = g * 2;
  __shared__ __align__(16) float Wl[8][516];   // [u][k], pad -> conflict-free
  __shared__ __align__(16) float hl[16][516];  // [b][k], 2-way (free)
  __shared__ float glds[16][8];
  __shared__ float cl[16][2];

  // stage W_hh slice (once; reused 512 steps)
  for (int i = tid; i < 8 * 512; i += 128) {
    const int uu = i & 7, k = i >> 3;
    const int col = (uu >> 1) * HS + j0 + (uu & 1);
    Wl[uu][k] = whh[k * G4H + col];
  }
  if (tid < 32) cl[tid >> 1][tid & 1] = 0.f;
  __syncthreads();

  const int mycol = (u >> 1) * HS + j0 + (u & 1);
  const float* hp = &hl[b][0];
  const float* wp = &Wl[u][0];

  for (int t = 0; t < TT; ++t) {
    // issue gates load early; read-only input so stale-cache is fine,
    // and it stays in flight across the poll loop (no use before dot).
    const float gxv = gates[(b * TT + t) * G4H + mycol];
    float acc;
    if (t > 0) {
      // wait until all 256 blocks published h_{t-1} (flags[g] >= t)
      unsigned f;
      do {
        f = __hip_atomic_load(&flags[tid], __ATOMIC_ACQUIRE,
                              __HIP_MEMORY_SCOPE_AGENT);
        if (f < (unsigned)t) __builtin_amdgcn_s_sleep(1);
      } while (f < (unsigned)t);
      do {
        f = __hip_atomic_load(&flags[tid + 128], __ATOMIC_ACQUIRE,
                              __HIP_MEMORY_SCOPE_AGENT);
        if (f < (unsigned)t) __builtin_amdgcn_s_sleep(1);
      } while (f < (unsigned)t);
      __syncthreads();
      // bulk reload of h_{t-1}: plain vector loads (fresh post-acquire)
      const float* hsrc = hbuf + ((t - 1) & 1) * (BB * HS);
      for (int i = tid * 4; i < BB * HS; i += 128 * 4)
        *(float4*)&hl[i >> 9][i & 511] = *(const float4*)&hsrc[i];
      __syncthreads();
      float4 a4 = {0.f, 0.f, 0.f, 0.f};
      #pragma unroll 4
      for (int k = 0; k < HS; k += 4) {
        const float4 hv = *(const float4*)(hp + k);
        const float4 wv = *(const float4*)(wp + k);
        a4.x = fmaf(hv.x, wv.x, a4.x);
        a4.y = fmaf(hv.y, wv.y, a4.y);
        a4.z = fmaf(hv.z, wv.z, a4.z);
        a4.w = fmaf(hv.w, wv.w, a4.w);
      }
      acc = gxv + (a4.x + a4.y) + (a4.z + a4.w);
    } else {
      acc = gxv;
    }
    glds[b][u] = acc;
    __syncthreads();
    if (tid < 32) {
      const int bb = tid >> 1, jj = tid & 1;
      const float iv = glds[bb][0 + jj];
      const float fv = glds[bb][2 + jj];
      const float gv = glds[bb][4 + jj];
      const float ov = glds[bb][6 + jj];
      const float ig = 1.f / (1.f + expf(-iv));
      const float fg = 1.f / (1.f + expf(-fv));
      const float gg = tanhf(gv);
      const float og = 1.f / (1.f + expf(-ov));
      const float c = fg * cl[bb][jj] + ig * gg;
      cl[bb][jj] = c;
      const float h = og * tanhf(c);
      const int unit = j0 + jj;
      out[(bb * TT + t) * HS + unit] = h;  // hidden_seq
      // publish h: write-through atomic store straight to LLC
      float* hdst = hbuf + (t & 1) * (BB * HS);
      __hip_atomic_store((unsigned int*)&hdst[bb * HS + unit],
                         __float_as_uint(h), __ATOMIC_RELAXED,
                         __HIP_MEMORY_SCOPE_AGENT);
      if (t == TT - 1) {
        out[BB * TT * HS + bb * HS + unit] = h;            // h_t
        out[BB * TT * HS + BB * HS + bb * HS + unit] = c;  // c_t
      }
    }
    __syncthreads();  // h-stores of tid<32 happen-before tid0's release
    if (tid == 0)
      __hip_atomic_store(&flags[g], (unsigned)(t + 1), __ATOMIC_RELEASE,
                         __HIP_MEMORY_SCOPE_AGENT);
  }
}

// ============================================================
extern "C" void kernel_launch(void* const* d_in, const int* in_sizes, int n_in,
                              void* d_out, int out_size, void* d_ws,
                              size_t ws_size, hipStream_t stream) {
  const float* x    = (const float*)d_in[0];
  const float* w1   = (const float*)d_in[1];
  const float* b1   = (const float*)d_in[2];
  const float* w2   = (const float*)d_in[3];
  const float* b2   = (const float*)d_in[4];
  const float* wih  = (const float*)d_in[5];
  const float* whh  = (const float*)d_in[6];
  const float* bias = (const float*)d_in[7];
  float* out = (float*)d_out;

  float* ws = (float*)d_ws;
  float* s_buf  = ws;
  float* e_buf  = ws + 65536;
  float* i_buf  = ws + 131072;
  float* M_buf  = ws + 196608;
  float* g_buf  = ws + 2293760;
  float* h_buf  = ws + 19070976;
  unsigned int* flags = (unsigned int*)(ws + 19087360);

  // flags must start at 0 every call (ws is re-poisoned 0xAA -> huge values
  // would instantly satisfy every poll and race the pipeline)
  hipMemsetAsync(flags, 0, 256 * sizeof(unsigned int), stream);

  k1_score<<<512, 256, 0, stream>>>(x, w1, b1, w2, b2, s_buf);
  k2_prefix<<<BB * RR, 512, 0, stream>>>(s_buf, e_buf, i_buf);
  k3_mix<<<BB, 256, 0, stream>>>(x, e_buf, i_buf, M_buf);
  k4_gemm<<<64 * 16, 256, 0, stream>>>(M_buf, wih, bias, g_buf);
  k5_lstm<<<256, 128, 0, stream>>>(g_buf, whh, out, h_buf, flags);
}

// Round 3
// 12317.970 us; speedup vs baseline: 1.8784x; 1.1739x over previous
//
#include <hip/hip_runtime.h>
#include <math.h>

// Problem constants (reference: B,T,D=16,512,256; HS=512, D_A=64, R=8)
#define BB 16
#define TT 512
#define DD 256
#define HS 512
#define DA 64
#define RR 8
#define G4H 2048   // 4*HS

// -------- workspace layout (float offsets) --------
// s     :        0  (B*T*R      =    65536)
// e     :    65536  (B*T*R      =    65536)
// inv   :   131072  (B*T*R      =    65536)
// M     :   196608  (B*T*D      =  2097152)
// gates :  2293760  (B*T*4H     = 16777216)
// hbuf  : 19070976  (2*8*2*512  =    16384)
// flags : 19087360  (256 uints)

// ============================================================
// K1: s[b,t,r] = tanh(x[b,t,:] @ w1 + b1) @ w2 + b2
// ============================================================
__global__ __launch_bounds__(256) void k1_score(
    const float* __restrict__ x, const float* __restrict__ w1,
    const float* __restrict__ b1, const float* __restrict__ w2,
    const float* __restrict__ b2, float* __restrict__ s_out) {
  const int wave = threadIdx.x >> 6;
  const int lane = threadIdx.x & 63;
  for (int i = 0; i < 4; ++i) {
    const int bt = blockIdx.x * 16 + wave * 4 + i;  // grid=512 -> 8192 bt
    const float* xr = x + bt * DD;
    float acc = b1[lane];
    #pragma unroll 4
    for (int d = 0; d < DD; ++d)
      acc = fmaf(xr[d], w1[d * DA + lane], acc);   // w1 coalesced over lanes
    const float a = tanhf(acc);
    #pragma unroll
    for (int r = 0; r < RR; ++r) {
      float v = a * w2[lane * RR + r];
      for (int off = 32; off > 0; off >>= 1) v += __shfl_xor(v, off);
      if (lane == 0) s_out[bt * RR + r] = v + b2[r];
    }
  }
}

// ============================================================
// K2: per (b,r): m=max_t s; e=exp(s-m); den=inclusive prefix sum
// ============================================================
__global__ __launch_bounds__(512) void k2_prefix(
    const float* __restrict__ s_in, float* __restrict__ e_out,
    float* __restrict__ inv_out) {
  const int b = blockIdx.x >> 3, r = blockIdx.x & 7;
  const int t = threadIdx.x;
  __shared__ float red[TT];
  __shared__ float buf[2][TT];
  const float v = s_in[(b * TT + t) * RR + r];
  red[t] = v;
  __syncthreads();
  for (int off = 256; off >= 1; off >>= 1) {
    if (t < off) red[t] = fmaxf(red[t], red[t + off]);
    __syncthreads();
  }
  const float m = red[0];
  const float e = expf(v - m);
  int p = 0;
  buf[0][t] = e;
  __syncthreads();
  for (int off = 1; off < TT; off <<= 1) {
    const float add = (t >= off) ? buf[p][t - off] : 0.f;
    buf[1 - p][t] = buf[p][t] + add;
    __syncthreads();
    p ^= 1;
  }
  const float den = buf[p][t];
  e_out[(b * TT + t) * RR + r] = e;
  inv_out[(b * TT + t) * RR + r] = 1.0f / den;
}

// ============================================================
// K3: M[b,t,d] = (1/R) * sum_r inv[t,r] * prefix_j<=t( e[j,r]*x[b,j,d] )
// ============================================================
__global__ __launch_bounds__(256) void k3_mix(
    const float* __restrict__ x, const float* __restrict__ e_in,
    const float* __restrict__ inv_in, float* __restrict__ Mout) {
  const int b = blockIdx.x;
  const int d = threadIdx.x;
  __shared__ __align__(16) float el[TT * RR];
  __shared__ __align__(16) float il[TT * RR];
  for (int i = threadIdx.x; i < TT * RR; i += 256) {
    el[i] = e_in[b * TT * RR + i];
    il[i] = inv_in[b * TT * RR + i];
  }
  __syncthreads();
  float4 c0 = {0.f, 0.f, 0.f, 0.f}, c1 = {0.f, 0.f, 0.f, 0.f};
  for (int t = 0; t < TT; ++t) {
    const float xv = x[(b * TT + t) * DD + d];
    const float4 e0 = *(const float4*)&el[t * RR];
    const float4 e1 = *(const float4*)&el[t * RR + 4];
    const float4 i0 = *(const float4*)&il[t * RR];
    const float4 i1 = *(const float4*)&il[t * RR + 4];
    c0.x = fmaf(e0.x, xv, c0.x); c0.y = fmaf(e0.y, xv, c0.y);
    c0.z = fmaf(e0.z, xv, c0.z); c0.w = fmaf(e0.w, xv, c0.w);
    c1.x = fmaf(e1.x, xv, c1.x); c1.y = fmaf(e1.y, xv, c1.y);
    c1.z = fmaf(e1.z, xv, c1.z); c1.w = fmaf(e1.w, xv, c1.w);
    float msum = c0.x * i0.x + c0.y * i0.y + c0.z * i0.z + c0.w * i0.w;
    msum += c1.x * i1.x + c1.y * i1.y + c1.z * i1.z + c1.w * i1.w;
    Mout[(b * TT + t) * DD + d] = msum * 0.125f;
  }
}

// ============================================================
// K4: gates = M(8192x256) @ W_ih(256x2048) + bias   (fp32 SGEMM)
// ============================================================
__global__ __launch_bounds__(256) void k4_gemm(
    const float* __restrict__ A, const float* __restrict__ Bw,
    const float* __restrict__ bias, float* __restrict__ C) {
  const int bn = blockIdx.x & 15;
  const int bm = blockIdx.x >> 4;
  const int tid = threadIdx.x;
  const int tx = tid & 15, ty = tid >> 4;
  __shared__ __align__(16) float As[16][132];
  __shared__ __align__(16) float Bs[16][132];
  const int row0 = bm * 128, col0 = bn * 128;

  float acc[2][4][2][4];
  #pragma unroll
  for (int a = 0; a < 2; ++a)
    #pragma unroll
    for (int i = 0; i < 4; ++i)
      #pragma unroll
      for (int q = 0; q < 2; ++q)
        #pragma unroll
        for (int j = 0; j < 4; ++j) acc[a][i][q][j] = 0.f;

  const int arow = tid >> 1, akc = (tid & 1) * 8;
  const int bkr = tid >> 4, bcc = (tid & 15) * 8;

  for (int k0 = 0; k0 < 256; k0 += 16) {
    const float4 a0 = *(const float4*)&A[(row0 + arow) * 256 + k0 + akc];
    const float4 a1 = *(const float4*)&A[(row0 + arow) * 256 + k0 + akc + 4];
    const float4 b0 = *(const float4*)&Bw[(k0 + bkr) * 2048 + col0 + bcc];
    const float4 b1 = *(const float4*)&Bw[(k0 + bkr) * 2048 + col0 + bcc + 4];
    __syncthreads();
    As[akc + 0][arow] = a0.x; As[akc + 1][arow] = a0.y;
    As[akc + 2][arow] = a0.z; As[akc + 3][arow] = a0.w;
    As[akc + 4][arow] = a1.x; As[akc + 5][arow] = a1.y;
    As[akc + 6][arow] = a1.z; As[akc + 7][arow] = a1.w;
    *(float4*)&Bs[bkr][bcc] = b0;
    *(float4*)&Bs[bkr][bcc + 4] = b1;
    __syncthreads();
    #pragma unroll
    for (int kk = 0; kk < 16; ++kk) {
      float av[8], bv[8];
      *(float4*)&av[0] = *(const float4*)&As[kk][ty * 4];
      *(float4*)&av[4] = *(const float4*)&As[kk][64 + ty * 4];
      *(float4*)&bv[0] = *(const float4*)&Bs[kk][tx * 4];
      *(float4*)&bv[4] = *(const float4*)&Bs[kk][64 + tx * 4];
      #pragma unroll
      for (int a = 0; a < 2; ++a)
        #pragma unroll
        for (int i = 0; i < 4; ++i)
          #pragma unroll
          for (int q = 0; q < 2; ++q)
            #pragma unroll
            for (int j = 0; j < 4; ++j)
              acc[a][i][q][j] = fmaf(av[a * 4 + i], bv[q * 4 + j], acc[a][i][q][j]);
    }
  }
  const float4 bias0 = *(const float4*)&bias[col0 + tx * 4];
  const float4 bias1 = *(const float4*)&bias[col0 + 64 + tx * 4];
  #pragma unroll
  for (int a = 0; a < 2; ++a)
    #pragma unroll
    for (int i = 0; i < 4; ++i) {
      const int row = row0 + a * 64 + ty * 4 + i;
      float4 v0, v1;
      v0.x = acc[a][i][0][0] + bias0.x; v0.y = acc[a][i][0][1] + bias0.y;
      v0.z = acc[a][i][0][2] + bias0.z; v0.w = acc[a][i][0][3] + bias0.w;
      v1.x = acc[a][i][1][0] + bias1.x; v1.y = acc[a][i][1][1] + bias1.y;
      v1.z = acc[a][i][1][2] + bias1.z; v1.w = acc[a][i][1][3] + bias1.w;
      *(float4*)&C[row * 2048 + col0 + tx * 4] = v0;
      *(float4*)&C[row * 2048 + col0 + 64 + tx * 4] = v1;
    }
}

#define FMA4(ACC, W4, HSC)                         \
  ACC.x = fmaf((W4).x, (HSC), ACC.x);              \
  ACC.y = fmaf((W4).y, (HSC), ACC.y);              \
  ACC.z = fmaf((W4).z, (HSC), ACC.z);              \
  ACC.w = fmaf((W4).w, (HSC), ACC.w);

// ============================================================
// K5 v3: batch-partitioned sync domains.
//   grid = 8 batch-groups (bg) x 32 unit-slices (s) = 256 blocks (1/CU).
//   Block owns batches {2bg,2bg+1} and units j0=s*16..+15 (64 gate cols).
//   LSTM chains are independent per batch -> sync only among the 32
//   blocks of a batch-group (8 independent chains, no global straggler).
//   W slice: staged LDS (coalesced) -> VGPRs wr[32] (128 regs), so the
//   per-step dot reads only h (4KB) from LDS (padded, broadcast-friendly).
//   Busy-spin poll (no s_sleep) keeps clocks up (R2: 96% idle -> DVFS).
//   Thread map: kq=tid&15 (k-chunk of 32), ccol=(tid>>4)*4 (4 gate cols).
// ============================================================
__global__ __launch_bounds__(256, 1) void k5_lstm(
    const float* __restrict__ gates, const float* __restrict__ whh,
    float* __restrict__ out, float* hbuf, unsigned int* flags) {
  const int s   = blockIdx.x & 31;
  const int bg  = blockIdx.x >> 5;
  const int tid = threadIdx.x;
  const int kq  = tid & 15;
  const int ccol = (tid >> 4) * 4;       // 0,4,...,60
  const int j0 = s * 16;
  const int b0 = bg * 2;

  __shared__ __align__(16) float Wl[512 * 64];  // [k][c] staging (131072 B)
  __shared__ __align__(16) float hl[2][528];    // padded: addr = k + (k>>5)
  __shared__ __align__(16) float gfin[2][64];
  __shared__ float cl[32];

  // ---- stage W slice (coalesced rows), once ----
  for (int i = tid; i < 512 * 64; i += 256) {
    const int c = i & 63, k = i >> 6;
    Wl[k * 64 + c] = whh[k * G4H + (c >> 4) * HS + j0 + (c & 15)];
  }
  if (tid < 32) cl[tid] = 0.f;
  __syncthreads();

  // ---- LDS -> VGPRs: thread holds W[k in kq*32..+31][ccol..ccol+3] ----
  float4 wr[32];
  #pragma unroll
  for (int k_i = 0; k_i < 32; ++k_i)
    wr[k_i] = *(const float4*)&Wl[(kq * 32 + k_i) * 64 + ccol];

  const int gate = ccol >> 4, jj = ccol & 15;
  const float* gp0 = gates + ((long)b0 * TT) * G4H + gate * HS + j0 + jj;
  const float* gp1 = gp0 + (long)TT * G4H;
  const unsigned fidx = bg * 32 + (tid & 31);
  float h_keep = 0.f;

  for (int t = 0; t < TT; ++t) {
    // prefetch gates (lanes kq==0 only; in flight across the poll)
    float4 gx0 = {0, 0, 0, 0}, gx1 = {0, 0, 0, 0};
    if (kq == 0) {
      gx0 = *(const float4*)&gp0[(long)t * G4H];
      gx1 = *(const float4*)&gp1[(long)t * G4H];
    }
    float4 acc0 = {0, 0, 0, 0}, acc1 = {0, 0, 0, 0};
    if (t > 0) {
      // busy-spin until all 32 group members published h_{t-1}
      unsigned f;
      do {
        f = __hip_atomic_load(&flags[fidx], __ATOMIC_ACQUIRE,
                              __HIP_MEMORY_SCOPE_AGENT);
      } while (f < (unsigned)t);
      __syncthreads();
      // reload h (2 batches x 512) into padded LDS
      const float* hsrc = hbuf + (((t - 1) & 1) * 8 + bg) * 1024;
      {
        const int i4 = tid * 4;
        const int bb = i4 >> 9, k = i4 & 511;
        const float4 hv = *(const float4*)&hsrc[i4];
        const int pa = k + (k >> 5);
        hl[bb][pa] = hv.x; hl[bb][pa + 1] = hv.y;
        hl[bb][pa + 2] = hv.z; hl[bb][pa + 3] = hv.w;
      }
      __syncthreads();
      // dot: acc[bb][4 cols] += W[k][c] * h[bb][k] over k-chunk
      const float* hb0 = &hl[0][kq * 33];
      const float* hb1 = &hl[1][kq * 33];
      #pragma unroll
      for (int i = 0; i < 8; ++i) {
        const float4 h0 = *(const float4*)(hb0 + i * 4);
        const float4 h1 = *(const float4*)(hb1 + i * 4);
        FMA4(acc0, wr[i * 4 + 0], h0.x); FMA4(acc1, wr[i * 4 + 0], h1.x);
        FMA4(acc0, wr[i * 4 + 1], h0.y); FMA4(acc1, wr[i * 4 + 1], h1.y);
        FMA4(acc0, wr[i * 4 + 2], h0.z); FMA4(acc1, wr[i * 4 + 2], h1.z);
        FMA4(acc0, wr[i * 4 + 3], h0.w); FMA4(acc1, wr[i * 4 + 3], h1.w);
      }
    }
    // reduce over kq (16 lanes) via butterfly shuffles
    #pragma unroll
    for (int off = 1; off <= 8; off <<= 1) {
      acc0.x += __shfl_xor(acc0.x, off); acc0.y += __shfl_xor(acc0.y, off);
      acc0.z += __shfl_xor(acc0.z, off); acc0.w += __shfl_xor(acc0.w, off);
      acc1.x += __shfl_xor(acc1.x, off); acc1.y += __shfl_xor(acc1.y, off);
      acc1.z += __shfl_xor(acc1.z, off); acc1.w += __shfl_xor(acc1.w, off);
    }
    if (kq == 0) {
      float4 g0, g1;
      g0.x = acc0.x + gx0.x; g0.y = acc0.y + gx0.y;
      g0.z = acc0.z + gx0.z; g0.w = acc0.w + gx0.w;
      g1.x = acc1.x + gx1.x; g1.y = acc1.y + gx1.y;
      g1.z = acc1.z + gx1.z; g1.w = acc1.w + gx1.w;
      *(float4*)&gfin[0][ccol] = g0;
      *(float4*)&gfin[1][ccol] = g1;
    }
    __syncthreads();
    // epilogue + publish + flag: all in wave 0 (release drains THIS wave's
    // vmem queue -> h stores are covered; other waves have none pending)
    if (tid < 32) {
      const int bb = tid >> 4, j = tid & 15;
      const float iv = gfin[bb][j];
      const float fv = gfin[bb][16 + j];
      const float gv = gfin[bb][32 + j];
      const float ov = gfin[bb][48 + j];
      const float ig = 1.f / (1.f + expf(-iv));
      const float fg = 1.f / (1.f + expf(-fv));
      const float gg = tanhf(gv);
      const float og = 1.f / (1.f + expf(-ov));
      const float c = fg * cl[tid] + ig * gg;
      cl[tid] = c;
      const float h = og * tanhf(c);
      h_keep = h;
      const int unit = j0 + j;
      float* hdst = hbuf + ((t & 1) * 8 + bg) * 1024 + bb * 512;
      __hip_atomic_store((unsigned int*)&hdst[unit], __float_as_uint(h),
                         __ATOMIC_RELAXED, __HIP_MEMORY_SCOPE_AGENT);
      if (t == TT - 1) {
        out[(long)BB * TT * HS + (b0 + bb) * HS + unit] = h;            // h_t
        out[(long)BB * TT * HS + BB * HS + (b0 + bb) * HS + unit] = c;  // c_t
      }
    }
    if (tid == 0)
      __hip_atomic_store(&flags[bg * 32 + s], (unsigned)(t + 1),
                         __ATOMIC_RELEASE, __HIP_MEMORY_SCOPE_AGENT);
    // hidden_seq store AFTER the flag release: off the critical path
    if (tid < 32) {
      const int bb = tid >> 4, j = tid & 15;
      out[((long)(b0 + bb) * TT + t) * HS + j0 + j] = h_keep;
    }
    // no end-of-loop barrier needed: next step's poll cannot pass until
    // this block's own flag (set by wave 0 above) reaches t+1, and the
    // poll is followed by __syncthreads before hl/gfin are overwritten.
  }
}

// ============================================================
extern "C" void kernel_launch(void* const* d_in, const int* in_sizes, int n_in,
                              void* d_out, int out_size, void* d_ws,
                              size_t ws_size, hipStream_t stream) {
  const float* x    = (const float*)d_in[0];
  const float* w1   = (const float*)d_in[1];
  const float* b1   = (const float*)d_in[2];
  const float* w2   = (const float*)d_in[3];
  const float* b2   = (const float*)d_in[4];
  const float* wih  = (const float*)d_in[5];
  const float* whh  = (const float*)d_in[6];
  const float* bias = (const float*)d_in[7];
  float* out = (float*)d_out;

  float* ws = (float*)d_ws;
  float* s_buf  = ws;
  float* e_buf  = ws + 65536;
  float* i_buf  = ws + 131072;
  float* M_buf  = ws + 196608;
  float* g_buf  = ws + 2293760;
  float* h_buf  = ws + 19070976;
  unsigned int* flags = (unsigned int*)(ws + 19087360);

  // flags must start at 0 every call (ws re-poisoned 0xAA)
  hipMemsetAsync(flags, 0, 256 * sizeof(unsigned int), stream);

  k1_score<<<512, 256, 0, stream>>>(x, w1, b1, w2, b2, s_buf);
  k2_prefix<<<BB * RR, 512, 0, stream>>>(s_buf, e_buf, i_buf);
  k3_mix<<<BB, 256, 0, stream>>>(x, e_buf, i_buf, M_buf);
  k4_gemm<<<64 * 16, 256, 0, stream>>>(M_buf, wih, bias, g_buf);
  k5_lstm<<<256, 256, 0, stream>>>(g_buf, whh, out, h_buf, flags);
}

// Round 4
// 2631.416 us; speedup vs baseline: 8.7928x; 4.6811x over previous
//
#include <hip/hip_runtime.h>
#include <math.h>

// Problem constants (reference: B,T,D=16,512,256; HS=512, D_A=64, R=8)
#define BB 16
#define TT 512
#define DD 256
#define HS 512
#define DA 64
#define RR 8
#define G4H 2048   // 4*HS

// -------- workspace layout (float offsets) --------
// s     :        0  (B*T*R      =    65536)
// e     :    65536  (B*T*R      =    65536)
// inv   :   131072  (B*T*R      =    65536)
// M     :   196608  (B*T*D      =  2097152)
// gates :  2293760  (B*T*4H     = 16777216)
// hbuf  : 19070976  (2*8*2*512  =    16384)
// flags : 19087360  (256 uints)

// ============================================================
// K1: s[b,t,r] = tanh(x[b,t,:] @ w1 + b1) @ w2 + b2
// ============================================================
__global__ __launch_bounds__(256) void k1_score(
    const float* __restrict__ x, const float* __restrict__ w1,
    const float* __restrict__ b1, const float* __restrict__ w2,
    const float* __restrict__ b2, float* __restrict__ s_out) {
  const int wave = threadIdx.x >> 6;
  const int lane = threadIdx.x & 63;
  for (int i = 0; i < 4; ++i) {
    const int bt = blockIdx.x * 16 + wave * 4 + i;  // grid=512 -> 8192 bt
    const float* xr = x + bt * DD;
    float acc = b1[lane];
    #pragma unroll 4
    for (int d = 0; d < DD; ++d)
      acc = fmaf(xr[d], w1[d * DA + lane], acc);   // w1 coalesced over lanes
    const float a = tanhf(acc);
    #pragma unroll
    for (int r = 0; r < RR; ++r) {
      float v = a * w2[lane * RR + r];
      for (int off = 32; off > 0; off >>= 1) v += __shfl_xor(v, off);
      if (lane == 0) s_out[bt * RR + r] = v + b2[r];
    }
  }
}

// ============================================================
// K2: per (b,r): m=max_t s; e=exp(s-m); den=inclusive prefix sum
// ============================================================
__global__ __launch_bounds__(512) void k2_prefix(
    const float* __restrict__ s_in, float* __restrict__ e_out,
    float* __restrict__ inv_out) {
  const int b = blockIdx.x >> 3, r = blockIdx.x & 7;
  const int t = threadIdx.x;
  __shared__ float red[TT];
  __shared__ float buf[2][TT];
  const float v = s_in[(b * TT + t) * RR + r];
  red[t] = v;
  __syncthreads();
  for (int off = 256; off >= 1; off >>= 1) {
    if (t < off) red[t] = fmaxf(red[t], red[t + off]);
    __syncthreads();
  }
  const float m = red[0];
  const float e = expf(v - m);
  int p = 0;
  buf[0][t] = e;
  __syncthreads();
  for (int off = 1; off < TT; off <<= 1) {
    const float add = (t >= off) ? buf[p][t - off] : 0.f;
    buf[1 - p][t] = buf[p][t] + add;
    __syncthreads();
    p ^= 1;
  }
  const float den = buf[p][t];
  e_out[(b * TT + t) * RR + r] = e;
  inv_out[(b * TT + t) * RR + r] = 1.0f / den;
}

// ============================================================
// K3: M[b,t,d] = (1/R) * sum_r inv[t,r] * prefix_j<=t( e[j,r]*x[b,j,d] )
// ============================================================
__global__ __launch_bounds__(256) void k3_mix(
    const float* __restrict__ x, const float* __restrict__ e_in,
    const float* __restrict__ inv_in, float* __restrict__ Mout) {
  const int b = blockIdx.x;
  const int d = threadIdx.x;
  __shared__ __align__(16) float el[TT * RR];
  __shared__ __align__(16) float il[TT * RR];
  for (int i = threadIdx.x; i < TT * RR; i += 256) {
    el[i] = e_in[b * TT * RR + i];
    il[i] = inv_in[b * TT * RR + i];
  }
  __syncthreads();
  float4 c0 = {0.f, 0.f, 0.f, 0.f}, c1 = {0.f, 0.f, 0.f, 0.f};
  for (int t = 0; t < TT; ++t) {
    const float xv = x[(b * TT + t) * DD + d];
    const float4 e0 = *(const float4*)&el[t * RR];
    const float4 e1 = *(const float4*)&el[t * RR + 4];
    const float4 i0 = *(const float4*)&il[t * RR];
    const float4 i1 = *(const float4*)&il[t * RR + 4];
    c0.x = fmaf(e0.x, xv, c0.x); c0.y = fmaf(e0.y, xv, c0.y);
    c0.z = fmaf(e0.z, xv, c0.z); c0.w = fmaf(e0.w, xv, c0.w);
    c1.x = fmaf(e1.x, xv, c1.x); c1.y = fmaf(e1.y, xv, c1.y);
    c1.z = fmaf(e1.z, xv, c1.z); c1.w = fmaf(e1.w, xv, c1.w);
    float msum = c0.x * i0.x + c0.y * i0.y + c0.z * i0.z + c0.w * i0.w;
    msum += c1.x * i1.x + c1.y * i1.y + c1.z * i1.z + c1.w * i1.w;
    Mout[(b * TT + t) * DD + d] = msum * 0.125f;
  }
}

// ============================================================
// K4: gates = M(8192x256) @ W_ih(256x2048) + bias   (fp32 SGEMM)
// ============================================================
__global__ __launch_bounds__(256) void k4_gemm(
    const float* __restrict__ A, const float* __restrict__ Bw,
    const float* __restrict__ bias, float* __restrict__ C) {
  const int bn = blockIdx.x & 15;
  const int bm = blockIdx.x >> 4;
  const int tid = threadIdx.x;
  const int tx = tid & 15, ty = tid >> 4;
  __shared__ __align__(16) float As[16][132];
  __shared__ __align__(16) float Bs[16][132];
  const int row0 = bm * 128, col0 = bn * 128;

  float acc[2][4][2][4];
  #pragma unroll
  for (int a = 0; a < 2; ++a)
    #pragma unroll
    for (int i = 0; i < 4; ++i)
      #pragma unroll
      for (int q = 0; q < 2; ++q)
        #pragma unroll
        for (int j = 0; j < 4; ++j) acc[a][i][q][j] = 0.f;

  const int arow = tid >> 1, akc = (tid & 1) * 8;
  const int bkr = tid >> 4, bcc = (tid & 15) * 8;

  for (int k0 = 0; k0 < 256; k0 += 16) {
    const float4 a0 = *(const float4*)&A[(row0 + arow) * 256 + k0 + akc];
    const float4 a1 = *(const float4*)&A[(row0 + arow) * 256 + k0 + akc + 4];
    const float4 b0 = *(const float4*)&Bw[(k0 + bkr) * 2048 + col0 + bcc];
    const float4 b1 = *(const float4*)&Bw[(k0 + bkr) * 2048 + col0 + bcc + 4];
    __syncthreads();
    As[akc + 0][arow] = a0.x; As[akc + 1][arow] = a0.y;
    As[akc + 2][arow] = a0.z; As[akc + 3][arow] = a0.w;
    As[akc + 4][arow] = a1.x; As[akc + 5][arow] = a1.y;
    As[akc + 6][arow] = a1.z; As[akc + 7][arow] = a1.w;
    *(float4*)&Bs[bkr][bcc] = b0;
    *(float4*)&Bs[bkr][bcc + 4] = b1;
    __syncthreads();
    #pragma unroll
    for (int kk = 0; kk < 16; ++kk) {
      float av[8], bv[8];
      *(float4*)&av[0] = *(const float4*)&As[kk][ty * 4];
      *(float4*)&av[4] = *(const float4*)&As[kk][64 + ty * 4];
      *(float4*)&bv[0] = *(const float4*)&Bs[kk][tx * 4];
      *(float4*)&bv[4] = *(const float4*)&Bs[kk][64 + tx * 4];
      #pragma unroll
      for (int a = 0; a < 2; ++a)
        #pragma unroll
        for (int i = 0; i < 4; ++i)
          #pragma unroll
          for (int q = 0; q < 2; ++q)
            #pragma unroll
            for (int j = 0; j < 4; ++j)
              acc[a][i][q][j] = fmaf(av[a * 4 + i], bv[q * 4 + j], acc[a][i][q][j]);
    }
  }
  const float4 bias0 = *(const float4*)&bias[col0 + tx * 4];
  const float4 bias1 = *(const float4*)&bias[col0 + 64 + tx * 4];
  #pragma unroll
  for (int a = 0; a < 2; ++a)
    #pragma unroll
    for (int i = 0; i < 4; ++i) {
      const int row = row0 + a * 64 + ty * 4 + i;
      float4 v0, v1;
      v0.x = acc[a][i][0][0] + bias0.x; v0.y = acc[a][i][0][1] + bias0.y;
      v0.z = acc[a][i][0][2] + bias0.z; v0.w = acc[a][i][0][3] + bias0.w;
      v1.x = acc[a][i][1][0] + bias1.x; v1.y = acc[a][i][1][1] + bias1.y;
      v1.z = acc[a][i][1][2] + bias1.z; v1.w = acc[a][i][1][3] + bias1.w;
      *(float4*)&C[row * 2048 + col0 + tx * 4] = v0;
      *(float4*)&C[row * 2048 + col0 + 64 + tx * 4] = v1;
    }
}

#define FMA4(ACC, W4, HSC)                         \
  ACC.x = fmaf((W4).x, (HSC), ACC.x);              \
  ACC.y = fmaf((W4).y, (HSC), ACC.y);              \
  ACC.z = fmaf((W4).z, (HSC), ACC.z);              \
  ACC.w = fmaf((W4).w, (HSC), ACC.w);

// Relaxed agent-scope word load/store: go straight to LLC, NO buffer_inv /
// buffer_wbl2 cache maintenance (that was R3's 23us/step).
__device__ __forceinline__ float llc_load(const float* p) {
  return __uint_as_float(__hip_atomic_load((const unsigned int*)p,
                                           __ATOMIC_RELAXED,
                                           __HIP_MEMORY_SCOPE_AGENT));
}
__device__ __forceinline__ void llc_store(float* p, float v) {
  __hip_atomic_store((unsigned int*)p, __float_as_uint(v), __ATOMIC_RELAXED,
                     __HIP_MEMORY_SCOPE_AGENT);
}

// ============================================================
// K5 v4: same partition as v3 (8 batch-groups x 32 unit-slices; block owns
// 2 batches x 16 units; W in VGPRs; sync only within the 32-block group),
// but the sync protocol uses ONLY relaxed agent atomics:
//   producer: relaxed h stores -> s_waitcnt vmcnt(0) (own stores reached
//             LLC) -> relaxed flag store.   [no buffer_wbl2]
//   consumer: wave0 relaxed-polls 32 flags -> __syncthreads -> relaxed
//             h loads (LLC direct; committed-before-flag => fresh).
//             [no buffer_inv per poll iteration]
// ============================================================
__global__ __launch_bounds__(256, 1) void k5_lstm(
    const float* __restrict__ gates, const float* __restrict__ whh,
    float* __restrict__ out, float* hbuf, unsigned int* flags) {
  const int s   = blockIdx.x & 31;
  const int bg  = blockIdx.x >> 5;
  const int tid = threadIdx.x;
  const int kq  = tid & 15;
  const int ccol = (tid >> 4) * 4;       // 0,4,...,60
  const int j0 = s * 16;
  const int b0 = bg * 2;

  __shared__ __align__(16) float Wl[512 * 64];  // [k][c] staging (131072 B)
  __shared__ __align__(16) float hl[2][528];    // padded: addr = k + (k>>5)
  __shared__ __align__(16) float gfin[2][64];
  __shared__ float cl[32];

  // ---- stage W slice (coalesced rows), once ----
  for (int i = tid; i < 512 * 64; i += 256) {
    const int c = i & 63, k = i >> 6;
    Wl[k * 64 + c] = whh[k * G4H + (c >> 4) * HS + j0 + (c & 15)];
  }
  if (tid < 32) cl[tid] = 0.f;
  __syncthreads();

  // ---- LDS -> VGPRs: thread holds W[k in kq*32..+31][ccol..ccol+3] ----
  float4 wr[32];
  #pragma unroll
  for (int k_i = 0; k_i < 32; ++k_i)
    wr[k_i] = *(const float4*)&Wl[(kq * 32 + k_i) * 64 + ccol];

  const int gate = ccol >> 4, jj = ccol & 15;
  const float* gp0 = gates + ((long)b0 * TT) * G4H + gate * HS + j0 + jj;
  const float* gp1 = gp0 + (long)TT * G4H;
  float h_keep = 0.f;

  for (int t = 0; t < TT; ++t) {
    // prefetch gates (lanes kq==0 only; in flight across the poll)
    float4 gx0 = {0, 0, 0, 0}, gx1 = {0, 0, 0, 0};
    if (kq == 0) {
      gx0 = *(const float4*)&gp0[(long)t * G4H];
      gx1 = *(const float4*)&gp1[(long)t * G4H];
    }
    float4 acc0 = {0, 0, 0, 0}, acc1 = {0, 0, 0, 0};
    if (t > 0) {
      // wave0: busy-spin (relaxed, no cache ops) until the 32 group
      // members published h_{t-1}
      if (tid < 32) {
        unsigned f;
        do {
          f = __hip_atomic_load(&flags[bg * 32 + tid], __ATOMIC_RELAXED,
                                __HIP_MEMORY_SCOPE_AGENT);
        } while (f < (unsigned)t);
      }
      __syncthreads();
      // reload h (2 batches x 512) via relaxed LLC loads into padded LDS
      const float* hsrc = hbuf + (((t - 1) & 1) * 8 + bg) * 1024;
      {
        const int i4 = tid * 4;
        const int bb = i4 >> 9, k = i4 & 511;
        float h0 = llc_load(&hsrc[i4 + 0]);
        float h1 = llc_load(&hsrc[i4 + 1]);
        float h2 = llc_load(&hsrc[i4 + 2]);
        float h3 = llc_load(&hsrc[i4 + 3]);
        const int pa = k + (k >> 5);
        hl[bb][pa] = h0; hl[bb][pa + 1] = h1;
        hl[bb][pa + 2] = h2; hl[bb][pa + 3] = h3;
      }
      __syncthreads();
      // dot: acc[bb][4 cols] += W[k][c] * h[bb][k] over k-chunk
      const float* hb0 = &hl[0][kq * 33];
      const float* hb1 = &hl[1][kq * 33];
      #pragma unroll
      for (int i = 0; i < 8; ++i) {
        const float4 h0 = *(const float4*)(hb0 + i * 4);
        const float4 h1 = *(const float4*)(hb1 + i * 4);
        FMA4(acc0, wr[i * 4 + 0], h0.x); FMA4(acc1, wr[i * 4 + 0], h1.x);
        FMA4(acc0, wr[i * 4 + 1], h0.y); FMA4(acc1, wr[i * 4 + 1], h1.y);
        FMA4(acc0, wr[i * 4 + 2], h0.z); FMA4(acc1, wr[i * 4 + 2], h1.z);
        FMA4(acc0, wr[i * 4 + 3], h0.w); FMA4(acc1, wr[i * 4 + 3], h1.w);
      }
    }
    // reduce over kq (16 lanes) via butterfly shuffles
    #pragma unroll
    for (int off = 1; off <= 8; off <<= 1) {
      acc0.x += __shfl_xor(acc0.x, off); acc0.y += __shfl_xor(acc0.y, off);
      acc0.z += __shfl_xor(acc0.z, off); acc0.w += __shfl_xor(acc0.w, off);
      acc1.x += __shfl_xor(acc1.x, off); acc1.y += __shfl_xor(acc1.y, off);
      acc1.z += __shfl_xor(acc1.z, off); acc1.w += __shfl_xor(acc1.w, off);
    }
    if (kq == 0) {
      float4 g0, g1;
      g0.x = acc0.x + gx0.x; g0.y = acc0.y + gx0.y;
      g0.z = acc0.z + gx0.z; g0.w = acc0.w + gx0.w;
      g1.x = acc1.x + gx1.x; g1.y = acc1.y + gx1.y;
      g1.z = acc1.z + gx1.z; g1.w = acc1.w + gx1.w;
      *(float4*)&gfin[0][ccol] = g0;
      *(float4*)&gfin[1][ccol] = g1;
    }
    __syncthreads();
    // epilogue + publish (wave 0 only)
    if (tid < 32) {
      const int bb = tid >> 4, j = tid & 15;
      const float iv = gfin[bb][j];
      const float fv = gfin[bb][16 + j];
      const float gv = gfin[bb][32 + j];
      const float ov = gfin[bb][48 + j];
      const float ig = 1.f / (1.f + expf(-iv));
      const float fg = 1.f / (1.f + expf(-fv));
      const float gg = tanhf(gv);
      const float og = 1.f / (1.f + expf(-ov));
      const float c = fg * cl[tid] + ig * gg;
      cl[tid] = c;
      const float h = og * tanhf(c);
      h_keep = h;
      const int unit = j0 + j;
      float* hdst = hbuf + ((t & 1) * 8 + bg) * 1024 + bb * 512;
      llc_store(&hdst[unit], h);               // straight to LLC
      if (t == TT - 1) {
        out[(long)BB * TT * HS + (b0 + bb) * HS + unit] = h;            // h_t
        out[(long)BB * TT * HS + BB * HS + (b0 + bb) * HS + unit] = c;  // c_t
      }
      // hand-rolled release: wait THIS wave's stores to reach LLC, then
      // set the flag with a plain relaxed store. No L2 writeback.
      __asm__ __volatile__("s_waitcnt vmcnt(0)" ::: "memory");
      if (tid == 0)
        __hip_atomic_store(&flags[bg * 32 + s], (unsigned)(t + 1),
                           __ATOMIC_RELAXED, __HIP_MEMORY_SCOPE_AGENT);
    }
    // hidden_seq store AFTER the flag release: off the critical path
    if (tid < 32) {
      const int bb = tid >> 4, j = tid & 15;
      out[((long)(b0 + bb) * TT + t) * HS + j0 + j] = h_keep;
    }
    // no end-of-loop barrier needed: next step's poll (wave0) + its
    // __syncthreads gate every thread before hl/gfin are rewritten.
  }
}

// ============================================================
extern "C" void kernel_launch(void* const* d_in, const int* in_sizes, int n_in,
                              void* d_out, int out_size, void* d_ws,
                              size_t ws_size, hipStream_t stream) {
  const float* x    = (const float*)d_in[0];
  const float* w1   = (const float*)d_in[1];
  const float* b1   = (const float*)d_in[2];
  const float* w2   = (const float*)d_in[3];
  const float* b2   = (const float*)d_in[4];
  const float* wih  = (const float*)d_in[5];
  const float* whh  = (const float*)d_in[6];
  const float* bias = (const float*)d_in[7];
  float* out = (float*)d_out;

  float* ws = (float*)d_ws;
  float* s_buf  = ws;
  float* e_buf  = ws + 65536;
  float* i_buf  = ws + 131072;
  float* M_buf  = ws + 196608;
  float* g_buf  = ws + 2293760;
  float* h_buf  = ws + 19070976;
  unsigned int* flags = (unsigned int*)(ws + 19087360);

  // flags must start at 0 every call (ws re-poisoned 0xAA)
  hipMemsetAsync(flags, 0, 256 * sizeof(unsigned int), stream);

  k1_score<<<512, 256, 0, stream>>>(x, w1, b1, w2, b2, s_buf);
  k2_prefix<<<BB * RR, 512, 0, stream>>>(s_buf, e_buf, i_buf);
  k3_mix<<<BB, 256, 0, stream>>>(x, e_buf, i_buf, M_buf);
  k4_gemm<<<64 * 16, 256, 0, stream>>>(M_buf, wih, bias, g_buf);
  k5_lstm<<<256, 256, 0, stream>>>(g_buf, whh, out, h_buf, flags);
}

// Round 5
// 2113.841 us; speedup vs baseline: 10.9458x; 1.2449x over previous
//
#include <hip/hip_runtime.h>
#include <math.h>

// Problem constants (reference: B,T,D=16,512,256; HS=512, D_A=64, R=8)
#define BB 16
#define TT 512
#define DD 256
#define HS 512
#define DA 64
#define RR 8
#define G4H 2048   // 4*HS

// -------- workspace layout (float offsets) --------
// s     :        0  (B*T*R      =    65536)
// e     :    65536  (B*T*R      =    65536)
// inv   :   131072  (B*T*R      =    65536)
// M     :   196608  (B*T*D      =  2097152)
// gates :  2293760  (B*T*4H     = 16777216)
// hbuf  : 19070976  (2*16*512   =    16384)
// flags : 19087360  (256 uints)

// ============================================================
// K1: s[b,t,r] = tanh(x[b,t,:] @ w1 + b1) @ w2 + b2
// ============================================================
__global__ __launch_bounds__(256) void k1_score(
    const float* __restrict__ x, const float* __restrict__ w1,
    const float* __restrict__ b1, const float* __restrict__ w2,
    const float* __restrict__ b2, float* __restrict__ s_out) {
  const int wave = threadIdx.x >> 6;
  const int lane = threadIdx.x & 63;
  for (int i = 0; i < 4; ++i) {
    const int bt = blockIdx.x * 16 + wave * 4 + i;  // grid=512 -> 8192 bt
    const float* xr = x + bt * DD;
    float acc = b1[lane];
    #pragma unroll 4
    for (int d = 0; d < DD; ++d)
      acc = fmaf(xr[d], w1[d * DA + lane], acc);   // w1 coalesced over lanes
    const float a = tanhf(acc);
    #pragma unroll
    for (int r = 0; r < RR; ++r) {
      float v = a * w2[lane * RR + r];
      for (int off = 32; off > 0; off >>= 1) v += __shfl_xor(v, off);
      if (lane == 0) s_out[bt * RR + r] = v + b2[r];
    }
  }
}

// ============================================================
// K2: per (b,r): m=max_t s; e=exp(s-m); den=inclusive prefix sum
// ============================================================
__global__ __launch_bounds__(512) void k2_prefix(
    const float* __restrict__ s_in, float* __restrict__ e_out,
    float* __restrict__ inv_out) {
  const int b = blockIdx.x >> 3, r = blockIdx.x & 7;
  const int t = threadIdx.x;
  __shared__ float red[TT];
  __shared__ float buf[2][TT];
  const float v = s_in[(b * TT + t) * RR + r];
  red[t] = v;
  __syncthreads();
  for (int off = 256; off >= 1; off >>= 1) {
    if (t < off) red[t] = fmaxf(red[t], red[t + off]);
    __syncthreads();
  }
  const float m = red[0];
  const float e = expf(v - m);
  int p = 0;
  buf[0][t] = e;
  __syncthreads();
  for (int off = 1; off < TT; off <<= 1) {
    const float add = (t >= off) ? buf[p][t - off] : 0.f;
    buf[1 - p][t] = buf[p][t] + add;
    __syncthreads();
    p ^= 1;
  }
  const float den = buf[p][t];
  e_out[(b * TT + t) * RR + r] = e;
  inv_out[(b * TT + t) * RR + r] = 1.0f / den;
}

// ============================================================
// K3: M[b,t,d] = (1/R) * sum_r inv[t,r] * prefix_j<=t( e[j,r]*x[b,j,d] )
// 64 blocks x 64 threads (4x the CUs of the old 16x256 version)
// ============================================================
__global__ __launch_bounds__(64) void k3_mix(
    const float* __restrict__ x, const float* __restrict__ e_in,
    const float* __restrict__ inv_in, float* __restrict__ Mout) {
  const int b = blockIdx.x >> 2;
  const int d = (blockIdx.x & 3) * 64 + threadIdx.x;
  __shared__ __align__(16) float el[TT * RR];
  __shared__ __align__(16) float il[TT * RR];
  for (int i = threadIdx.x * 4; i < TT * RR; i += 64 * 4) {
    *(float4*)&el[i] = *(const float4*)&e_in[b * TT * RR + i];
    *(float4*)&il[i] = *(const float4*)&inv_in[b * TT * RR + i];
  }
  __syncthreads();
  float4 c0 = {0.f, 0.f, 0.f, 0.f}, c1 = {0.f, 0.f, 0.f, 0.f};
  for (int t = 0; t < TT; ++t) {
    const float xv = x[(b * TT + t) * DD + d];
    const float4 e0 = *(const float4*)&el[t * RR];
    const float4 e1 = *(const float4*)&el[t * RR + 4];
    const float4 i0 = *(const float4*)&il[t * RR];
    const float4 i1 = *(const float4*)&il[t * RR + 4];
    c0.x = fmaf(e0.x, xv, c0.x); c0.y = fmaf(e0.y, xv, c0.y);
    c0.z = fmaf(e0.z, xv, c0.z); c0.w = fmaf(e0.w, xv, c0.w);
    c1.x = fmaf(e1.x, xv, c1.x); c1.y = fmaf(e1.y, xv, c1.y);
    c1.z = fmaf(e1.z, xv, c1.z); c1.w = fmaf(e1.w, xv, c1.w);
    float msum = c0.x * i0.x + c0.y * i0.y + c0.z * i0.z + c0.w * i0.w;
    msum += c1.x * i1.x + c1.y * i1.y + c1.z * i1.z + c1.w * i1.w;
    Mout[(b * TT + t) * DD + d] = msum * 0.125f;
  }
}

// ============================================================
// K4: gates = M(8192x256) @ W_ih(256x2048) + bias   (fp32 SGEMM)
// ============================================================
__global__ __launch_bounds__(256) void k4_gemm(
    const float* __restrict__ A, const float* __restrict__ Bw,
    const float* __restrict__ bias, float* __restrict__ C) {
  const int bn = blockIdx.x & 15;
  const int bm = blockIdx.x >> 4;
  const int tid = threadIdx.x;
  const int tx = tid & 15, ty = tid >> 4;
  __shared__ __align__(16) float As[16][132];
  __shared__ __align__(16) float Bs[16][132];
  const int row0 = bm * 128, col0 = bn * 128;

  float acc[2][4][2][4];
  #pragma unroll
  for (int a = 0; a < 2; ++a)
    #pragma unroll
    for (int i = 0; i < 4; ++i)
      #pragma unroll
      for (int q = 0; q < 2; ++q)
        #pragma unroll
        for (int j = 0; j < 4; ++j) acc[a][i][q][j] = 0.f;

  const int arow = tid >> 1, akc = (tid & 1) * 8;
  const int bkr = tid >> 4, bcc = (tid & 15) * 8;

  for (int k0 = 0; k0 < 256; k0 += 16) {
    const float4 a0 = *(const float4*)&A[(row0 + arow) * 256 + k0 + akc];
    const float4 a1 = *(const float4*)&A[(row0 + arow) * 256 + k0 + akc + 4];
    const float4 b0 = *(const float4*)&Bw[(k0 + bkr) * 2048 + col0 + bcc];
    const float4 b1 = *(const float4*)&Bw[(k0 + bkr) * 2048 + col0 + bcc + 4];
    __syncthreads();
    As[akc + 0][arow] = a0.x; As[akc + 1][arow] = a0.y;
    As[akc + 2][arow] = a0.z; As[akc + 3][arow] = a0.w;
    As[akc + 4][arow] = a1.x; As[akc + 5][arow] = a1.y;
    As[akc + 6][arow] = a1.z; As[akc + 7][arow] = a1.w;
    *(float4*)&Bs[bkr][bcc] = b0;
    *(float4*)&Bs[bkr][bcc + 4] = b1;
    __syncthreads();
    #pragma unroll
    for (int kk = 0; kk < 16; ++kk) {
      float av[8], bv[8];
      *(float4*)&av[0] = *(const float4*)&As[kk][ty * 4];
      *(float4*)&av[4] = *(const float4*)&As[kk][64 + ty * 4];
      *(float4*)&bv[0] = *(const float4*)&Bs[kk][tx * 4];
      *(float4*)&bv[4] = *(const float4*)&Bs[kk][64 + tx * 4];
      #pragma unroll
      for (int a = 0; a < 2; ++a)
        #pragma unroll
        for (int i = 0; i < 4; ++i)
          #pragma unroll
          for (int q = 0; q < 2; ++q)
            #pragma unroll
            for (int j = 0; j < 4; ++j)
              acc[a][i][q][j] = fmaf(av[a * 4 + i], bv[q * 4 + j], acc[a][i][q][j]);
    }
  }
  const float4 bias0 = *(const float4*)&bias[col0 + tx * 4];
  const float4 bias1 = *(const float4*)&bias[col0 + 64 + tx * 4];
  #pragma unroll
  for (int a = 0; a < 2; ++a)
    #pragma unroll
    for (int i = 0; i < 4; ++i) {
      const int row = row0 + a * 64 + ty * 4 + i;
      float4 v0, v1;
      v0.x = acc[a][i][0][0] + bias0.x; v0.y = acc[a][i][0][1] + bias0.y;
      v0.z = acc[a][i][0][2] + bias0.z; v0.w = acc[a][i][0][3] + bias0.w;
      v1.x = acc[a][i][1][0] + bias1.x; v1.y = acc[a][i][1][1] + bias1.y;
      v1.z = acc[a][i][1][2] + bias1.z; v1.w = acc[a][i][1][3] + bias1.w;
      *(float4*)&C[row * 2048 + col0 + tx * 4] = v0;
      *(float4*)&C[row * 2048 + col0 + 64 + tx * 4] = v1;
    }
}

#define FMA4(ACC, W4, HSC)                         \
  ACC.x = fmaf((W4).x, (HSC), ACC.x);              \
  ACC.y = fmaf((W4).y, (HSC), ACC.y);              \
  ACC.z = fmaf((W4).z, (HSC), ACC.z);              \
  ACC.w = fmaf((W4).w, (HSC), ACC.w);

// Relaxed agent-scope word load/store: straight to LLC, NO buffer_inv /
// buffer_wbl2 cache maintenance (R4's 5.3x win).
__device__ __forceinline__ float llc_load(const float* p) {
  return __uint_as_float(__hip_atomic_load((const unsigned int*)p,
                                           __ATOMIC_RELAXED,
                                           __HIP_MEMORY_SCOPE_AGENT));
}
__device__ __forceinline__ void llc_store(float* p, float v) {
  __hip_atomic_store((unsigned int*)p, __float_as_uint(v), __ATOMIC_RELAXED,
                     __HIP_MEMORY_SCOPE_AGENT);
}

// ============================================================
// K5 v5: 16 INDEPENDENT per-batch domains x 16 blocks (32 units each).
// vs v4 (8 domains x 32 blocks, 2 batches): half the per-thread work
// (128 FMAs), half the poll fan-in (16 flags), straggler max-of-16,
// h reload = exactly 1 dword/thread, and 512-thread blocks -> 2
// waves/SIMD for latency overlap. W slice (512x128 = 256KB) lives in
// VGPRs (32 float4/thread), staged via LDS in two coalesced rounds.
// Sync protocol: relaxed-only atomics + s_waitcnt vmcnt(0) release
// (identical to v4 -- no cache maintenance ops).
// ============================================================
__global__ __launch_bounds__(512, 2) void k5_lstm(
    const float* __restrict__ gates, const float* __restrict__ whh,
    float* __restrict__ out, float* hbuf, unsigned int* flags) {
  const int s   = blockIdx.x & 15;       // unit-slice
  const int b   = blockIdx.x >> 4;       // batch = sync domain
  const int tid = threadIdx.x;           // 512 threads
  const int kq  = tid & 15;              // k-chunk: k in [kq*32, kq*32+32)
  const int cq  = tid >> 4;              // col-group: 4 cols of 128
  const int j0  = s * 32;
  const int gate = cq >> 3;              // 0..3
  const int uj   = (cq & 7) * 4;         // unit offset 0..28

  __shared__ __align__(16) float Wl[256 * 128];  // staging, 128 KB
  __shared__ __align__(16) float hl[512];
  __shared__ __align__(16) float gfin[128];      // [gate*32 + unit]

  // ---- stage W slice -> VGPRs in 2 coalesced rounds of 256 rows ----
  float4 wr[32];
  for (int rnd = 0; rnd < 2; ++rnd) {
    __syncthreads();
    for (int i = tid * 4; i < 256 * 128; i += 512 * 4) {
      const int k = i >> 7, c = i & 127;
      *(float4*)&Wl[i] =
          *(const float4*)&whh[(rnd * 256 + k) * G4H + (c >> 5) * HS + j0 + (c & 31)];
    }
    __syncthreads();
    if ((kq >> 3) == rnd) {
      const int kb = (kq & 7) * 32;
      #pragma unroll
      for (int kk = 0; kk < 32; ++kk)
        wr[kk] = *(const float4*)&Wl[(kb + kk) * 128 + cq * 4];
    }
  }

  const float* gp = gates + ((long)b * TT) * G4H + gate * HS + j0 + uj;
  float c_reg = 0.f;   // cell state, lanes tid<32 (unit j = tid)
  float h_keep = 0.f;

  for (int t = 0; t < TT; ++t) {
    // prefetch gates (kq==0 lanes; in flight across the poll)
    float4 gx = {0, 0, 0, 0};
    if (kq == 0) gx = *(const float4*)&gp[(long)t * G4H];
    float4 acc = {0, 0, 0, 0};
    if (t > 0) {
      // poll the 16 domain members' flags (relaxed, no cache ops)
      if (tid < 16) {
        unsigned f;
        do {
          f = __hip_atomic_load(&flags[b * 16 + tid], __ATOMIC_RELAXED,
                                __HIP_MEMORY_SCOPE_AGENT);
        } while (f < (unsigned)t);
      }
      __syncthreads();
      // reload h_{t-1}: one dword per thread from LLC
      const float* hsrc = hbuf + (((t - 1) & 1) * BB + b) * HS;
      hl[tid] = llc_load(&hsrc[tid]);
      __syncthreads();
      // dot: acc[4 cols] += W[k][c] * h[k] over this thread's k-chunk
      const float* hb = &hl[kq * 32];
      #pragma unroll
      for (int i = 0; i < 8; ++i) {
        const float4 h4 = *(const float4*)(hb + i * 4);  // broadcast read
        FMA4(acc, wr[i * 4 + 0], h4.x);
        FMA4(acc, wr[i * 4 + 1], h4.y);
        FMA4(acc, wr[i * 4 + 2], h4.z);
        FMA4(acc, wr[i * 4 + 3], h4.w);
      }
    }
    // reduce over kq (16 lanes within the wave)
    #pragma unroll
    for (int off = 1; off <= 8; off <<= 1) {
      acc.x += __shfl_xor(acc.x, off); acc.y += __shfl_xor(acc.y, off);
      acc.z += __shfl_xor(acc.z, off); acc.w += __shfl_xor(acc.w, off);
    }
    if (kq == 0) {
      float4 g4;
      g4.x = acc.x + gx.x; g4.y = acc.y + gx.y;
      g4.z = acc.z + gx.z; g4.w = acc.w + gx.w;
      *(float4*)&gfin[gate * 32 + uj] = g4;
    }
    __syncthreads();
    // epilogue + publish: wave0 lanes 0..31, unit j = tid
    if (tid < 32) {
      const int j = tid;
      const float iv = gfin[j];
      const float fv = gfin[32 + j];
      const float gv = gfin[64 + j];
      const float ov = gfin[96 + j];
      const float ig = 1.f / (1.f + expf(-iv));
      const float fg = 1.f / (1.f + expf(-fv));
      const float gg = tanhf(gv);
      const float og = 1.f / (1.f + expf(-ov));
      c_reg = fg * c_reg + ig * gg;
      const float h = og * tanhf(c_reg);
      h_keep = h;
      const int unit = j0 + j;
      float* hdst = hbuf + ((t & 1) * BB + b) * HS;
      llc_store(&hdst[unit], h);               // straight to LLC
      if (t == TT - 1) {
        out[(long)BB * TT * HS + b * HS + unit] = h;            // h_t
        out[(long)BB * TT * HS + BB * HS + b * HS + unit] = c_reg;  // c_t
      }
      // hand-rolled release: wave0's own stores reach LLC, then flag
      __asm__ __volatile__("s_waitcnt vmcnt(0)" ::: "memory");
      if (tid == 0)
        __hip_atomic_store(&flags[b * 16 + s], (unsigned)(t + 1),
                           __ATOMIC_RELAXED, __HIP_MEMORY_SCOPE_AGENT);
    }
    // hidden_seq store AFTER the flag release: off the critical path
    if (tid < 32)
      out[((long)b * TT + t) * HS + j0 + tid] = h_keep;
    // no end-of-loop barrier: next step's post-poll __syncthreads gates
    // every thread before hl/gfin are rewritten.
  }
}

// ============================================================
extern "C" void kernel_launch(void* const* d_in, const int* in_sizes, int n_in,
                              void* d_out, int out_size, void* d_ws,
                              size_t ws_size, hipStream_t stream) {
  const float* x    = (const float*)d_in[0];
  const float* w1   = (const float*)d_in[1];
  const float* b1   = (const float*)d_in[2];
  const float* w2   = (const float*)d_in[3];
  const float* b2   = (const float*)d_in[4];
  const float* wih  = (const float*)d_in[5];
  const float* whh  = (const float*)d_in[6];
  const float* bias = (const float*)d_in[7];
  float* out = (float*)d_out;

  float* ws = (float*)d_ws;
  float* s_buf  = ws;
  float* e_buf  = ws + 65536;
  float* i_buf  = ws + 131072;
  float* M_buf  = ws + 196608;
  float* g_buf  = ws + 2293760;
  float* h_buf  = ws + 19070976;
  unsigned int* flags = (unsigned int*)(ws + 19087360);

  // flags must start at 0 every call (ws re-poisoned 0xAA)
  hipMemsetAsync(flags, 0, 256 * sizeof(unsigned int), stream);

  k1_score<<<512, 256, 0, stream>>>(x, w1, b1, w2, b2, s_buf);
  k2_prefix<<<BB * RR, 512, 0, stream>>>(s_buf, e_buf, i_buf);
  k3_mix<<<64, 64, 0, stream>>>(x, e_buf, i_buf, M_buf);
  k4_gemm<<<64 * 16, 256, 0, stream>>>(M_buf, wih, bias, g_buf);
  k5_lstm<<<256, 512, 0, stream>>>(g_buf, whh, out, h_buf, flags);
}

// Round 6
// 1344.692 us; speedup vs baseline: 17.2066x; 1.5720x over previous
//
#include <hip/hip_runtime.h>
#include <math.h>

// Problem constants (reference: B,T,D=16,512,256; HS=512, D_A=64, R=8)
#define BB 16
#define TT 512
#define DD 256
#define HS 512
#define DA 64
#define RR 8
#define G4H 2048   // 4*HS

// -------- workspace layout (float offsets) --------
// s     :        0  (B*T*R =  65536)  <- k5's hbuf64 overlays this (dead by k4)
// e     :    65536
// inv   :   131072
// M     :   196608  (B*T*D   = 2097152)
// gates :  2293760  (B*T*4H  = 16777216)

// ============================================================
// K1: s[b,t,r] = tanh(x[b,t,:] @ w1 + b1) @ w2 + b2
// ============================================================
__global__ __launch_bounds__(256) void k1_score(
    const float* __restrict__ x, const float* __restrict__ w1,
    const float* __restrict__ b1, const float* __restrict__ w2,
    const float* __restrict__ b2, float* __restrict__ s_out) {
  const int wave = threadIdx.x >> 6;
  const int lane = threadIdx.x & 63;
  for (int i = 0; i < 4; ++i) {
    const int bt = blockIdx.x * 16 + wave * 4 + i;  // grid=512 -> 8192 bt
    const float* xr = x + bt * DD;
    float acc = b1[lane];
    #pragma unroll 4
    for (int d = 0; d < DD; ++d)
      acc = fmaf(xr[d], w1[d * DA + lane], acc);   // w1 coalesced over lanes
    const float a = tanhf(acc);
    #pragma unroll
    for (int r = 0; r < RR; ++r) {
      float v = a * w2[lane * RR + r];
      for (int off = 32; off > 0; off >>= 1) v += __shfl_xor(v, off);
      if (lane == 0) s_out[bt * RR + r] = v + b2[r];
    }
  }
}

// ============================================================
// K2: per (b,r): m=max_t s; e=exp(s-m); den=inclusive prefix sum
// ============================================================
__global__ __launch_bounds__(512) void k2_prefix(
    const float* __restrict__ s_in, float* __restrict__ e_out,
    float* __restrict__ inv_out) {
  const int b = blockIdx.x >> 3, r = blockIdx.x & 7;
  const int t = threadIdx.x;
  __shared__ float red[TT];
  __shared__ float buf[2][TT];
  const float v = s_in[(b * TT + t) * RR + r];
  red[t] = v;
  __syncthreads();
  for (int off = 256; off >= 1; off >>= 1) {
    if (t < off) red[t] = fmaxf(red[t], red[t + off]);
    __syncthreads();
  }
  const float m = red[0];
  const float e = expf(v - m);
  int p = 0;
  buf[0][t] = e;
  __syncthreads();
  for (int off = 1; off < TT; off <<= 1) {
    const float add = (t >= off) ? buf[p][t - off] : 0.f;
    buf[1 - p][t] = buf[p][t] + add;
    __syncthreads();
    p ^= 1;
  }
  const float den = buf[p][t];
  e_out[(b * TT + t) * RR + r] = e;
  inv_out[(b * TT + t) * RR + r] = 1.0f / den;
}

// ============================================================
// K3: M[b,t,d] = (1/R) * sum_r inv[t,r] * prefix_j<=t( e[j,r]*x[b,j,d] )
// ============================================================
__global__ __launch_bounds__(64) void k3_mix(
    const float* __restrict__ x, const float* __restrict__ e_in,
    const float* __restrict__ inv_in, float* __restrict__ Mout) {
  const int b = blockIdx.x >> 2;
  const int d = (blockIdx.x & 3) * 64 + threadIdx.x;
  __shared__ __align__(16) float el[TT * RR];
  __shared__ __align__(16) float il[TT * RR];
  for (int i = threadIdx.x * 4; i < TT * RR; i += 64 * 4) {
    *(float4*)&el[i] = *(const float4*)&e_in[b * TT * RR + i];
    *(float4*)&il[i] = *(const float4*)&inv_in[b * TT * RR + i];
  }
  __syncthreads();
  float4 c0 = {0.f, 0.f, 0.f, 0.f}, c1 = {0.f, 0.f, 0.f, 0.f};
  for (int t = 0; t < TT; ++t) {
    const float xv = x[(b * TT + t) * DD + d];
    const float4 e0 = *(const float4*)&el[t * RR];
    const float4 e1 = *(const float4*)&el[t * RR + 4];
    const float4 i0 = *(const float4*)&il[t * RR];
    const float4 i1 = *(const float4*)&il[t * RR + 4];
    c0.x = fmaf(e0.x, xv, c0.x); c0.y = fmaf(e0.y, xv, c0.y);
    c0.z = fmaf(e0.z, xv, c0.z); c0.w = fmaf(e0.w, xv, c0.w);
    c1.x = fmaf(e1.x, xv, c1.x); c1.y = fmaf(e1.y, xv, c1.y);
    c1.z = fmaf(e1.z, xv, c1.z); c1.w = fmaf(e1.w, xv, c1.w);
    float msum = c0.x * i0.x + c0.y * i0.y + c0.z * i0.z + c0.w * i0.w;
    msum += c1.x * i1.x + c1.y * i1.y + c1.z * i1.z + c1.w * i1.w;
    Mout[(b * TT + t) * DD + d] = msum * 0.125f;
  }
}

// ============================================================
// K4: gates = M(8192x256) @ W_ih(256x2048) + bias   (fp32 SGEMM)
// ============================================================
__global__ __launch_bounds__(256) void k4_gemm(
    const float* __restrict__ A, const float* __restrict__ Bw,
    const float* __restrict__ bias, float* __restrict__ C) {
  const int bn = blockIdx.x & 15;
  const int bm = blockIdx.x >> 4;
  const int tid = threadIdx.x;
  const int tx = tid & 15, ty = tid >> 4;
  __shared__ __align__(16) float As[16][132];
  __shared__ __align__(16) float Bs[16][132];
  const int row0 = bm * 128, col0 = bn * 128;

  float acc[2][4][2][4];
  #pragma unroll
  for (int a = 0; a < 2; ++a)
    #pragma unroll
    for (int i = 0; i < 4; ++i)
      #pragma unroll
      for (int q = 0; q < 2; ++q)
        #pragma unroll
        for (int j = 0; j < 4; ++j) acc[a][i][q][j] = 0.f;

  const int arow = tid >> 1, akc = (tid & 1) * 8;
  const int bkr = tid >> 4, bcc = (tid & 15) * 8;

  for (int k0 = 0; k0 < 256; k0 += 16) {
    const float4 a0 = *(const float4*)&A[(row0 + arow) * 256 + k0 + akc];
    const float4 a1 = *(const float4*)&A[(row0 + arow) * 256 + k0 + akc + 4];
    const float4 b0 = *(const float4*)&Bw[(k0 + bkr) * 2048 + col0 + bcc];
    const float4 b1 = *(const float4*)&Bw[(k0 + bkr) * 2048 + col0 + bcc + 4];
    __syncthreads();
    As[akc + 0][arow] = a0.x; As[akc + 1][arow] = a0.y;
    As[akc + 2][arow] = a0.z; As[akc + 3][arow] = a0.w;
    As[akc + 4][arow] = a1.x; As[akc + 5][arow] = a1.y;
    As[akc + 6][arow] = a1.z; As[akc + 7][arow] = a1.w;
    *(float4*)&Bs[bkr][bcc] = b0;
    *(float4*)&Bs[bkr][bcc + 4] = b1;
    __syncthreads();
    #pragma unroll
    for (int kk = 0; kk < 16; ++kk) {
      float av[8], bv[8];
      *(float4*)&av[0] = *(const float4*)&As[kk][ty * 4];
      *(float4*)&av[4] = *(const float4*)&As[kk][64 + ty * 4];
      *(float4*)&bv[0] = *(const float4*)&Bs[kk][tx * 4];
      *(float4*)&bv[4] = *(const float4*)&Bs[kk][64 + tx * 4];
      #pragma unroll
      for (int a = 0; a < 2; ++a)
        #pragma unroll
        for (int i = 0; i < 4; ++i)
          #pragma unroll
          for (int q = 0; q < 2; ++q)
            #pragma unroll
            for (int j = 0; j < 4; ++j)
              acc[a][i][q][j] = fmaf(av[a * 4 + i], bv[q * 4 + j], acc[a][i][q][j]);
    }
  }
  const float4 bias0 = *(const float4*)&bias[col0 + tx * 4];
  const float4 bias1 = *(const float4*)&bias[col0 + 64 + tx * 4];
  #pragma unroll
  for (int a = 0; a < 2; ++a)
    #pragma unroll
    for (int i = 0; i < 4; ++i) {
      const int row = row0 + a * 64 + ty * 4 + i;
      float4 v0, v1;
      v0.x = acc[a][i][0][0] + bias0.x; v0.y = acc[a][i][0][1] + bias0.y;
      v0.z = acc[a][i][0][2] + bias0.z; v0.w = acc[a][i][0][3] + bias0.w;
      v1.x = acc[a][i][1][0] + bias1.x; v1.y = acc[a][i][1][1] + bias1.y;
      v1.z = acc[a][i][1][2] + bias1.z; v1.w = acc[a][i][1][3] + bias1.w;
      *(float4*)&C[row * 2048 + col0 + tx * 4] = v0;
      *(float4*)&C[row * 2048 + col0 + 64 + tx * 4] = v1;
    }
}

#define FMA4(ACC, W4, HSC)                         \
  ACC.x = fmaf((W4).x, (HSC), ACC.x);              \
  ACC.y = fmaf((W4).y, (HSC), ACC.y);              \
  ACC.z = fmaf((W4).z, (HSC), ACC.z);              \
  ACC.w = fmaf((W4).w, (HSC), ACC.w);

// fast transcendentals: v_exp_f32 + v_rcp_f32 (~1e-6 err << 1.5e-2 tol)
__device__ __forceinline__ float fast_sigmoid(float x) {
  return __builtin_amdgcn_rcpf(1.f + __expf(-x));
}
__device__ __forceinline__ float fast_tanh(float x) {
  const float xc = fmaxf(x, -30.f);           // avoid inf*0 NaN
  const float e = __expf(-2.f * xc);
  return (1.f - e) * __builtin_amdgcn_rcpf(1.f + e);
}

// ============================================================
// K5 v6: 16 per-batch domains x 16 blocks (32 units each), 512 thr.
// Fixes vs v5 (post-mortem):
//  (1) __launch_bounds__(512,1): v5's (512,2) capped VGPRs at 128 ->
//      compiler demoted wr[32] (needs 128 regs) to per-step LDS
//      re-reads (VGPR_Count=112 was the tell). Grid is 1 block/CU
//      anyway; budget 256 keeps W truly register-resident.
//  (2) hl padded to stride 36/32-chunk (16B-aligned): v5's unpadded
//      layout made every dot ds_read_b128 16-way bank-conflicted
//      (SQ_LDS_BANK_CONFLICT 236M). 36-stride -> 2-way = free.
//  (3) tagged-packet sync: h published as atomic 8B (tag<<32|bits);
//      consumers poll their OWN word until tag>=t. One LLC hop
//      replaces flag-hop + vmcnt drain + separate h load. No fences,
//      no cache-maintenance ops. gfin parity-buffered; 2 syncs/step.
//      Safety: sync-A (post-gfin-write) gates hl overwrite (all dots
//      done); gfin[par] reuse at t+2 is gated through the remote
//      producer chain (P's t+1 publish needs our t publish, which
//      follows our epilogue's gfin[par] reads).
// ============================================================
__global__ __launch_bounds__(512, 1) void k5_lstm(
    const float* __restrict__ gates, const float* __restrict__ whh,
    float* __restrict__ out, unsigned long long* hbuf) {
  const int s   = blockIdx.x & 15;       // unit-slice
  const int b   = blockIdx.x >> 4;       // batch = sync domain
  const int tid = threadIdx.x;           // 512 threads
  const int kq  = tid & 15;              // k-chunk: k in [kq*32, kq*32+32)
  const int cq  = tid >> 4;              // col-group: 4 of 128 cols
  const int j0  = s * 32;
  const int gate = cq >> 3;              // 0..3
  const int uj   = (cq & 7) * 4;         // unit offset 0..28

  __shared__ __align__(16) float Wl[256 * 128];  // staging, 128 KB
  __shared__ __align__(16) float hl[576];        // padded: chunk*36 + pos
  __shared__ __align__(16) float gfin[2][128];   // parity-buffered

  // ---- stage W slice -> VGPRs in 2 coalesced rounds of 256 rows ----
  float4 wr[32];
  for (int rnd = 0; rnd < 2; ++rnd) {
    for (int i = tid * 4; i < 256 * 128; i += 512 * 4) {
      const int k = i >> 7, c = i & 127;
      *(float4*)&Wl[i] =
          *(const float4*)&whh[(rnd * 256 + k) * G4H + (c >> 5) * HS + j0 + (c & 31)];
    }
    __syncthreads();
    if ((kq >> 3) == rnd) {
      const int kb = (kq & 7) * 32;
      #pragma unroll
      for (int kk = 0; kk < 32; ++kk)
        wr[kk] = *(const float4*)&Wl[(kb + kk) * 128 + cq * 4];
    }
    __syncthreads();
  }

  const float* gp = gates + ((long)b * TT) * G4H + gate * HS + j0 + uj;
  float c_reg = 0.f;   // cell state (lanes tid<32; unit j = tid)
  float h_keep = 0.f;

  for (int t = 0; t < TT; ++t) {
    // gates prefetch (kq==0 lanes), in flight across the poll
    float4 gx = {0, 0, 0, 0};
    if (kq == 0) gx = *(const float4*)&gp[(long)t * G4H];
    float4 acc = {0, 0, 0, 0};
    if (t > 0) {
      // self-validating poll: my unit's packet for step t-1 (tag t)
      const unsigned long long* hsrc =
          hbuf + (((t - 1) & 1) * BB + b) * HS;
      unsigned long long pkt;
      do {
        pkt = __hip_atomic_load(&hsrc[tid], __ATOMIC_RELAXED,
                                __HIP_MEMORY_SCOPE_AGENT);
      } while ((unsigned)(pkt >> 32) < (unsigned)t);
      hl[(tid >> 5) * 36 + (tid & 31)] = __uint_as_float((unsigned)pkt);
      __syncthreads();  // sync-B: hl complete
      // dot: acc[4 cols] += W[k][c] * h[k] over this thread's k-chunk
      const float* hb = &hl[kq * 36];
      #pragma unroll
      for (int i = 0; i < 8; ++i) {
        const float4 h4 = *(const float4*)(hb + i * 4);
        FMA4(acc, wr[i * 4 + 0], h4.x);
        FMA4(acc, wr[i * 4 + 1], h4.y);
        FMA4(acc, wr[i * 4 + 2], h4.z);
        FMA4(acc, wr[i * 4 + 3], h4.w);
      }
    }
    // reduce over kq (16 lanes within the wave)
    #pragma unroll
    for (int off = 1; off <= 8; off <<= 1) {
      acc.x += __shfl_xor(acc.x, off); acc.y += __shfl_xor(acc.y, off);
      acc.z += __shfl_xor(acc.z, off); acc.w += __shfl_xor(acc.w, off);
    }
    if (kq == 0) {
      float4 g4;
      g4.x = acc.x + gx.x; g4.y = acc.y + gx.y;
      g4.z = acc.z + gx.z; g4.w = acc.w + gx.w;
      *(float4*)&gfin[t & 1][gate * 32 + uj] = g4;
    }
    __syncthreads();  // sync-A: gfin complete (also: all dots done)
    // epilogue + publish: lanes 0..31, unit j = tid
    if (tid < 32) {
      const int j = tid;
      const float* gf = gfin[t & 1];
      const float ig = fast_sigmoid(gf[j]);
      const float fg = fast_sigmoid(gf[32 + j]);
      const float gg = fast_tanh(gf[64 + j]);
      const float og = fast_sigmoid(gf[96 + j]);
      c_reg = fg * c_reg + ig * gg;
      const float h = og * fast_tanh(c_reg);
      h_keep = h;
      const int unit = j0 + j;
      // publish: one atomic 8B packet (tag t+1 | bits) straight to LLC
      const unsigned long long pkt =
          ((unsigned long long)(unsigned)(t + 1) << 32) |
          (unsigned long long)__float_as_uint(h);
      __hip_atomic_store(&hbuf[((t & 1) * BB + b) * HS + unit], pkt,
                         __ATOMIC_RELAXED, __HIP_MEMORY_SCOPE_AGENT);
      if (t == TT - 1) {
        out[(long)BB * TT * HS + b * HS + unit] = h;               // h_t
        out[(long)BB * TT * HS + BB * HS + b * HS + unit] = c_reg; // c_t
      }
    }
    // hidden_seq store after publish: off the critical path
    if (tid < 32)
      out[((long)b * TT + t) * HS + j0 + tid] = h_keep;
  }
}

// ============================================================
extern "C" void kernel_launch(void* const* d_in, const int* in_sizes, int n_in,
                              void* d_out, int out_size, void* d_ws,
                              size_t ws_size, hipStream_t stream) {
  const float* x    = (const float*)d_in[0];
  const float* w1   = (const float*)d_in[1];
  const float* b1   = (const float*)d_in[2];
  const float* w2   = (const float*)d_in[3];
  const float* b2   = (const float*)d_in[4];
  const float* wih  = (const float*)d_in[5];
  const float* whh  = (const float*)d_in[6];
  const float* bias = (const float*)d_in[7];
  float* out = (float*)d_out;

  float* ws = (float*)d_ws;
  float* s_buf  = ws;                    // 65536 floats; dead after k2
  float* e_buf  = ws + 65536;
  float* i_buf  = ws + 131072;
  float* M_buf  = ws + 196608;
  float* g_buf  = ws + 2293760;
  // hbuf64 overlays the s region (2*16*512 uint64 = 128 KB <= 256 KB)
  unsigned long long* hbuf64 = (unsigned long long*)ws;

  k1_score<<<512, 256, 0, stream>>>(x, w1, b1, w2, b2, s_buf);
  k2_prefix<<<BB * RR, 512, 0, stream>>>(s_buf, e_buf, i_buf);
  k3_mix<<<64, 64, 0, stream>>>(x, e_buf, i_buf, M_buf);
  k4_gemm<<<64 * 16, 256, 0, stream>>>(M_buf, wih, bias, g_buf);
  // zero the packet tags (ws re-poisoned 0xAA each call; 0xAAAAAAAA > any t
  // would instantly satisfy polls). Stream-ordered after k2's s_buf reads.
  hipMemsetAsync(hbuf64, 0, 2 * BB * HS * sizeof(unsigned long long), stream);
  k5_lstm<<<256, 512, 0, stream>>>(g_buf, whh, out, hbuf64);
}

// Round 7
// 1143.000 us; speedup vs baseline: 20.2429x; 1.1765x over previous
//
#include <hip/hip_runtime.h>
#include <math.h>

// Problem constants (reference: B,T,D=16,512,256; HS=512, D_A=64, R=8)
#define BB 16
#define TT 512
#define DD 256
#define HS 512
#define DA 64
#define RR 8
#define G4H 2048   // 4*HS

// -------- workspace layout (float offsets) --------
// s     :        0  (B*T*R =  65536)  <- k5's hbuf64 overlays this (dead by k4)
// e     :    65536
// inv   :   131072
// M     :   196608  (B*T*D   = 2097152)
// gates :  2293760  (B*T*4H  = 16777216)

// ============================================================
// K1: s[b,t,r] = tanh(x[b,t,:] @ w1 + b1) @ w2 + b2
// ============================================================
__global__ __launch_bounds__(256) void k1_score(
    const float* __restrict__ x, const float* __restrict__ w1,
    const float* __restrict__ b1, const float* __restrict__ w2,
    const float* __restrict__ b2, float* __restrict__ s_out) {
  const int wave = threadIdx.x >> 6;
  const int lane = threadIdx.x & 63;
  for (int i = 0; i < 4; ++i) {
    const int bt = blockIdx.x * 16 + wave * 4 + i;  // grid=512 -> 8192 bt
    const float* xr = x + bt * DD;
    float acc = b1[lane];
    #pragma unroll 4
    for (int d = 0; d < DD; ++d)
      acc = fmaf(xr[d], w1[d * DA + lane], acc);   // w1 coalesced over lanes
    const float a = tanhf(acc);
    #pragma unroll
    for (int r = 0; r < RR; ++r) {
      float v = a * w2[lane * RR + r];
      for (int off = 32; off > 0; off >>= 1) v += __shfl_xor(v, off);
      if (lane == 0) s_out[bt * RR + r] = v + b2[r];
    }
  }
}

// ============================================================
// K2: per (b,r): m=max_t s; e=exp(s-m); den=inclusive prefix sum
// ============================================================
__global__ __launch_bounds__(512) void k2_prefix(
    const float* __restrict__ s_in, float* __restrict__ e_out,
    float* __restrict__ inv_out) {
  const int b = blockIdx.x >> 3, r = blockIdx.x & 7;
  const int t = threadIdx.x;
  __shared__ float red[TT];
  __shared__ float buf[2][TT];
  const float v = s_in[(b * TT + t) * RR + r];
  red[t] = v;
  __syncthreads();
  for (int off = 256; off >= 1; off >>= 1) {
    if (t < off) red[t] = fmaxf(red[t], red[t + off]);
    __syncthreads();
  }
  const float m = red[0];
  const float e = expf(v - m);
  int p = 0;
  buf[0][t] = e;
  __syncthreads();
  for (int off = 1; off < TT; off <<= 1) {
    const float add = (t >= off) ? buf[p][t - off] : 0.f;
    buf[1 - p][t] = buf[p][t] + add;
    __syncthreads();
    p ^= 1;
  }
  const float den = buf[p][t];
  e_out[(b * TT + t) * RR + r] = e;
  inv_out[(b * TT + t) * RR + r] = 1.0f / den;
}

// ============================================================
// K3: M[b,t,d] = (1/R) * sum_r inv[t,r] * prefix_j<=t( e[j,r]*x[b,j,d] )
// ============================================================
__global__ __launch_bounds__(64) void k3_mix(
    const float* __restrict__ x, const float* __restrict__ e_in,
    const float* __restrict__ inv_in, float* __restrict__ Mout) {
  const int b = blockIdx.x >> 2;
  const int d = (blockIdx.x & 3) * 64 + threadIdx.x;
  __shared__ __align__(16) float el[TT * RR];
  __shared__ __align__(16) float il[TT * RR];
  for (int i = threadIdx.x * 4; i < TT * RR; i += 64 * 4) {
    *(float4*)&el[i] = *(const float4*)&e_in[b * TT * RR + i];
    *(float4*)&il[i] = *(const float4*)&inv_in[b * TT * RR + i];
  }
  __syncthreads();
  float4 c0 = {0.f, 0.f, 0.f, 0.f}, c1 = {0.f, 0.f, 0.f, 0.f};
  for (int t = 0; t < TT; ++t) {
    const float xv = x[(b * TT + t) * DD + d];
    const float4 e0 = *(const float4*)&el[t * RR];
    const float4 e1 = *(const float4*)&el[t * RR + 4];
    const float4 i0 = *(const float4*)&il[t * RR];
    const float4 i1 = *(const float4*)&il[t * RR + 4];
    c0.x = fmaf(e0.x, xv, c0.x); c0.y = fmaf(e0.y, xv, c0.y);
    c0.z = fmaf(e0.z, xv, c0.z); c0.w = fmaf(e0.w, xv, c0.w);
    c1.x = fmaf(e1.x, xv, c1.x); c1.y = fmaf(e1.y, xv, c1.y);
    c1.z = fmaf(e1.z, xv, c1.z); c1.w = fmaf(e1.w, xv, c1.w);
    float msum = c0.x * i0.x + c0.y * i0.y + c0.z * i0.z + c0.w * i0.w;
    msum += c1.x * i1.x + c1.y * i1.y + c1.z * i1.z + c1.w * i1.w;
    Mout[(b * TT + t) * DD + d] = msum * 0.125f;
  }
}

// ============================================================
// K4: gates = M(8192x256) @ W_ih(256x2048) + bias   (fp32 SGEMM)
// ============================================================
__global__ __launch_bounds__(256) void k4_gemm(
    const float* __restrict__ A, const float* __restrict__ Bw,
    const float* __restrict__ bias, float* __restrict__ C) {
  const int bn = blockIdx.x & 15;
  const int bm = blockIdx.x >> 4;
  const int tid = threadIdx.x;
  const int tx = tid & 15, ty = tid >> 4;
  __shared__ __align__(16) float As[16][132];
  __shared__ __align__(16) float Bs[16][132];
  const int row0 = bm * 128, col0 = bn * 128;

  float acc[2][4][2][4];
  #pragma unroll
  for (int a = 0; a < 2; ++a)
    #pragma unroll
    for (int i = 0; i < 4; ++i)
      #pragma unroll
      for (int q = 0; q < 2; ++q)
        #pragma unroll
        for (int j = 0; j < 4; ++j) acc[a][i][q][j] = 0.f;

  const int arow = tid >> 1, akc = (tid & 1) * 8;
  const int bkr = tid >> 4, bcc = (tid & 15) * 8;

  for (int k0 = 0; k0 < 256; k0 += 16) {
    const float4 a0 = *(const float4*)&A[(row0 + arow) * 256 + k0 + akc];
    const float4 a1 = *(const float4*)&A[(row0 + arow) * 256 + k0 + akc + 4];
    const float4 b0 = *(const float4*)&Bw[(k0 + bkr) * 2048 + col0 + bcc];
    const float4 b1 = *(const float4*)&Bw[(k0 + bkr) * 2048 + col0 + bcc + 4];
    __syncthreads();
    As[akc + 0][arow] = a0.x; As[akc + 1][arow] = a0.y;
    As[akc + 2][arow] = a0.z; As[akc + 3][arow] = a0.w;
    As[akc + 4][arow] = a1.x; As[akc + 5][arow] = a1.y;
    As[akc + 6][arow] = a1.z; As[akc + 7][arow] = a1.w;
    *(float4*)&Bs[bkr][bcc] = b0;
    *(float4*)&Bs[bkr][bcc + 4] = b1;
    __syncthreads();
    #pragma unroll
    for (int kk = 0; kk < 16; ++kk) {
      float av[8], bv[8];
      *(float4*)&av[0] = *(const float4*)&As[kk][ty * 4];
      *(float4*)&av[4] = *(const float4*)&As[kk][64 + ty * 4];
      *(float4*)&bv[0] = *(const float4*)&Bs[kk][tx * 4];
      *(float4*)&bv[4] = *(const float4*)&Bs[kk][64 + tx * 4];
      #pragma unroll
      for (int a = 0; a < 2; ++a)
        #pragma unroll
        for (int i = 0; i < 4; ++i)
          #pragma unroll
          for (int q = 0; q < 2; ++q)
            #pragma unroll
            for (int j = 0; j < 4; ++j)
              acc[a][i][q][j] = fmaf(av[a * 4 + i], bv[q * 4 + j], acc[a][i][q][j]);
    }
  }
  const float4 bias0 = *(const float4*)&bias[col0 + tx * 4];
  const float4 bias1 = *(const float4*)&bias[col0 + 64 + tx * 4];
  #pragma unroll
  for (int a = 0; a < 2; ++a)
    #pragma unroll
    for (int i = 0; i < 4; ++i) {
      const int row = row0 + a * 64 + ty * 4 + i;
      float4 v0, v1;
      v0.x = acc[a][i][0][0] + bias0.x; v0.y = acc[a][i][0][1] + bias0.y;
      v0.z = acc[a][i][0][2] + bias0.z; v0.w = acc[a][i][0][3] + bias0.w;
      v1.x = acc[a][i][1][0] + bias1.x; v1.y = acc[a][i][1][1] + bias1.y;
      v1.z = acc[a][i][1][2] + bias1.z; v1.w = acc[a][i][1][3] + bias1.w;
      *(float4*)&C[row * 2048 + col0 + tx * 4] = v0;
      *(float4*)&C[row * 2048 + col0 + 64 + tx * 4] = v1;
    }
}

#define FMA4(ACC, W4, HSC)                         \
  ACC.x = fmaf((W4).x, (HSC), ACC.x);              \
  ACC.y = fmaf((W4).y, (HSC), ACC.y);              \
  ACC.z = fmaf((W4).z, (HSC), ACC.z);              \
  ACC.w = fmaf((W4).w, (HSC), ACC.w);

// fast transcendentals: v_exp_f32 + v_rcp_f32 (~1e-6 err << 1.5e-2 tol)
__device__ __forceinline__ float fast_sigmoid(float x) {
  return __builtin_amdgcn_rcpf(1.f + __expf(-x));
}
__device__ __forceinline__ float fast_tanh(float x) {
  const float xc = fmaxf(x, -30.f);           // avoid inf*0 NaN
  const float e = __expf(-2.f * xc);
  return (1.f - e) * __builtin_amdgcn_rcpf(1.f + e);
}

// ============================================================
// K5 v7: 16 per-batch domains x 16 blocks (32 units), 512 thr.
// Fixes vs v6 (post-mortem):
//  (1) wr gather via VOLATILE LDS loads: v6's VGPR_Count=96 proved the
//      compiler rematerialized wr[32] into the K-loop as per-step
//      ds_reads (320 KB/step/CU LDS traffic = the 1.07us/step gap).
//      Volatile loads cannot be remat'd -> W truly register-resident.
//  (2) unit-major remap: thread (kq,cq) owns the 4 GATES of unit
//      j0+cq (wr = i,f,g,o columns). After the kq-butterfly, lane
//      kq==0 holds the unit's full (i,f,g,o) -> epilogue + packet
//      publish fused in-lane. Removes gfin round-trip + 2nd barrier:
//      ONE barrier/step, parity-buffered hl.
//      Race safety: barrier(t) sits between hl[p] writes and reads;
//      t+1 writes target hl[p^1], and every thread's t-1 reads of
//      hl[p^1] precede barrier(t) in program order.
// ============================================================
__global__ __launch_bounds__(512, 1) void k5_lstm(
    const float* __restrict__ gates, const float* __restrict__ whh,
    float* __restrict__ out, unsigned long long* hbuf) {
  const int s   = blockIdx.x & 15;       // unit-slice
  const int b   = blockIdx.x >> 4;       // batch = sync domain
  const int tid = threadIdx.x;           // 512 threads
  const int kq  = tid & 15;              // k-chunk: k in [kq*32, kq*32+32)
  const int cq  = tid >> 4;              // unit offset 0..31
  const int j0  = s * 32;
  const int unit = j0 + cq;

  __shared__ __align__(16) float Wl[256 * 128];  // staging, 128 KB
  __shared__ __align__(16) float hl[2][576];     // parity; chunk*36+pos

  // ---- stage W slice (coalesced) and gather into registers ----
  // wr[kk] = (W[k][i-col], W[k][f-col], W[k][g-col], W[k][o-col]) of
  // THIS thread's unit, k = (kq&7)*32 + kk + 256*(kq>>3)-round.
  float4 wr[32];
  for (int rnd = 0; rnd < 2; ++rnd) {
    for (int i = tid * 4; i < 256 * 128; i += 512 * 4) {
      const int k = i >> 7, c = i & 127;   // Wl[k][c], c = gate*32 + uo
      *(float4*)&Wl[i] =
          *(const float4*)&whh[(rnd * 256 + k) * G4H + (c >> 5) * HS + j0 + (c & 31)];
    }
    __syncthreads();
    if ((kq >> 3) == rnd) {
      const int kb = (kq & 7) * 32;
      #pragma unroll
      for (int kk = 0; kk < 32; ++kk) {
        const int base = (kb + kk) * 128 + cq;
        wr[kk].x = *(volatile const float*)&Wl[base];
        wr[kk].y = *(volatile const float*)&Wl[base + 32];
        wr[kk].z = *(volatile const float*)&Wl[base + 64];
        wr[kk].w = *(volatile const float*)&Wl[base + 96];
      }
    }
    __syncthreads();
  }

  float c_reg = 0.f;   // cell state (lives in lanes kq==0; unit j0+cq)

  for (int t = 0; t < TT; ++t) {
    // gate-x prefetch: 4 dwords (i,f,g,o of my unit), in flight over poll
    float gi = 0.f, gf = 0.f, gg = 0.f, go = 0.f;
    if (kq == 0) {
      const float* gt = gates + ((long)b * TT + t) * G4H + unit;
      gi = gt[0]; gf = gt[HS]; gg = gt[2 * HS]; go = gt[3 * HS];
    }
    const int par = t & 1;
    if (t > 0) {
      // self-validating poll of my own unit's packet (tag >= t)
      const unsigned long long* hsrc = hbuf + (((t - 1) & 1) * BB + b) * HS;
      unsigned long long pkt;
      do {
        pkt = __hip_atomic_load(&hsrc[tid], __ATOMIC_RELAXED,
                                __HIP_MEMORY_SCOPE_AGENT);
      } while ((unsigned)(pkt >> 32) < (unsigned)t);
      hl[par][(tid >> 5) * 36 + (tid & 31)] = __uint_as_float((unsigned)pkt);
    }
    __syncthreads();  // the ONE barrier: hl[par] complete
    float4 acc = {0.f, 0.f, 0.f, 0.f};
    if (t > 0) {
      const float* hb = &hl[par][kq * 36];
      #pragma unroll
      for (int i = 0; i < 8; ++i) {
        const float4 h4 = *(const float4*)(hb + i * 4);
        FMA4(acc, wr[i * 4 + 0], h4.x);
        FMA4(acc, wr[i * 4 + 1], h4.y);
        FMA4(acc, wr[i * 4 + 2], h4.z);
        FMA4(acc, wr[i * 4 + 3], h4.w);
      }
    }
    // butterfly over the 16 kq lanes (in-wave: group = 16 consecutive)
    #pragma unroll
    for (int off = 1; off <= 8; off <<= 1) {
      acc.x += __shfl_xor(acc.x, off); acc.y += __shfl_xor(acc.y, off);
      acc.z += __shfl_xor(acc.z, off); acc.w += __shfl_xor(acc.w, off);
    }
    // fused epilogue + publish: lane kq==0 has full (i,f,g,o) of unit
    if (kq == 0) {
      const float I = fast_sigmoid(acc.x + gi);
      const float F = fast_sigmoid(acc.y + gf);
      const float G = fast_tanh(acc.z + gg);
      const float O = fast_sigmoid(acc.w + go);
      c_reg = F * c_reg + I * G;
      const float h = O * fast_tanh(c_reg);
      const unsigned long long pkt =
          ((unsigned long long)(unsigned)(t + 1) << 32) |
          (unsigned long long)__float_as_uint(h);
      __hip_atomic_store(&hbuf[((t & 1) * BB + b) * HS + unit], pkt,
                         __ATOMIC_RELAXED, __HIP_MEMORY_SCOPE_AGENT);
      out[((long)b * TT + t) * HS + unit] = h;   // hidden_seq (post-publish)
      if (t == TT - 1) {
        out[(long)BB * TT * HS + b * HS + unit] = h;               // h_t
        out[(long)BB * TT * HS + BB * HS + b * HS + unit] = c_reg; // c_t
      }
    }
  }
}

// ============================================================
extern "C" void kernel_launch(void* const* d_in, const int* in_sizes, int n_in,
                              void* d_out, int out_size, void* d_ws,
                              size_t ws_size, hipStream_t stream) {
  const float* x    = (const float*)d_in[0];
  const float* w1   = (const float*)d_in[1];
  const float* b1   = (const float*)d_in[2];
  const float* w2   = (const float*)d_in[3];
  const float* b2   = (const float*)d_in[4];
  const float* wih  = (const float*)d_in[5];
  const float* whh  = (const float*)d_in[6];
  const float* bias = (const float*)d_in[7];
  float* out = (float*)d_out;

  float* ws = (float*)d_ws;
  float* s_buf  = ws;                    // 65536 floats; dead after k2
  float* e_buf  = ws + 65536;
  float* i_buf  = ws + 131072;
  float* M_buf  = ws + 196608;
  float* g_buf  = ws + 2293760;
  // hbuf64 overlays the s region (2*16*512 uint64 = 128 KB <= 256 KB)
  unsigned long long* hbuf64 = (unsigned long long*)ws;

  k1_score<<<512, 256, 0, stream>>>(x, w1, b1, w2, b2, s_buf);
  k2_prefix<<<BB * RR, 512, 0, stream>>>(s_buf, e_buf, i_buf);
  k3_mix<<<64, 64, 0, stream>>>(x, e_buf, i_buf, M_buf);
  k4_gemm<<<64 * 16, 256, 0, stream>>>(M_buf, wih, bias, g_buf);
  // zero the packet tags (ws re-poisoned 0xAA each call; 0xAAAAAAAA > any t
  // would instantly satisfy polls). Stream-ordered after k2's s_buf reads.
  hipMemsetAsync(hbuf64, 0, 2 * BB * HS * sizeof(unsigned long long), stream);
  k5_lstm<<<256, 512, 0, stream>>>(g_buf, whh, out, hbuf64);
}